// Round 2
// baseline (393.657 us; speedup 1.0000x reference)
//
#include <hip/hip_runtime.h>
#include <math.h>

#define N_NODES 100000
#define NFEAT 256
#define D1 64          // HEADS*NHID
#define HEADS 8
#define NHID 8
#define NCLASS 32
#define NUM_EDGES 1600000
#define E_TOT 1700000  // + self loops
#define NEG_SLOPE 0.2f

// dst-bucketing: 256 nodes per bucket; CSR stored bucket-strided (no compaction)
#define BSHIFT 8
#define NBUCK 391            // ceil(100000/256)
#define BCAP 5120            // mean edges/bucket 4352, std ~66; +11.6 sigma headroom
#define BIN_EPB 4096
#define BIN_EPT 16

// LESSON (r4): wave-per-node x 25k waves >> block-per-bucket (TLP hides gather latency).
// LESSON (r9/polish): gather1 @76us was latency-bound (VALUBusy 56%, HBM 30%, VGPR 12,
// 0 conflicts -> nothing saturated). Fix = MLP: 4 edge slots x 16 lanes x uint2 loads
// + 2-deep csr / 1-deep value software pipeline. Same for gather2. WORKED (-20us).
// LESSON (r10): gemm1 @69us was barrier-bound: 2x __syncthreads per K-chunk made all
// 4 waves ride the unprefetched global-load latency together (MfmaUtil 1.7%, VALU 12%,
// HBM 13% -- nothing saturated). Fix: drop LDS staging entirely; each lane loads its
// A-fragment direct from global (16-row x 32-col tile = 2x float4/lane, 128B/row
// segments). 4 waves/block re-read the same tile -> L2 hits (409MB L2 << 34.5TB/s).

// ---- workspace layout (float offsets); h1/h2 are PACKED BF16 (uint = 2 ch) ----
#define OFF_H1    0            // h1b: 3.2M uints; reused: h2b=[0,1.6M) uints, out2=[3.2M,6.4M) f32
#define OFF_OUT1  6400000      // f32
#define OFF_ALS1  12800000
#define OFF_ALD1  13600000
#define OFF_ALS2  14400000
#define OFF_ALD2  14500000
#define OFF_BCUR  14600000     // 391 ints (pad to 1024)
#define OFF_ROWP  14601024
#define OFF_CNT   14701024
#define OFF_BIN   14801024     // 391*5120 ints (packed dl<<20|src)
#define OFF_CSR   16802944     // 391*5120 ints (dst-sorted src)

typedef __attribute__((ext_vector_type(8))) short bf16x8;
typedef __attribute__((ext_vector_type(4))) float f32x4;

__device__ __forceinline__ float lrelu(float x) { return x >= 0.f ? x : NEG_SLOPE * x; }

__device__ __forceinline__ unsigned f32_to_bf16_rne(float f) {
    unsigned u = __float_as_uint(f);
    return (u + 0x7fffu + ((u >> 16) & 1u)) >> 16;
}
__device__ __forceinline__ unsigned pack_bf16x2(float lo, float hi) {
    return f32_to_bf16_rne(lo) | (f32_to_bf16_rne(hi) << 16);
}
__device__ __forceinline__ float2 unpack_bf16x2(unsigned v) {
    return make_float2(__uint_as_float(v << 16), __uint_as_float(v & 0xffff0000u));
}

__device__ __forceinline__ void edge_src_dst(const int* __restrict__ ei, int e, int& src, int& dst) {
    if (e < NUM_EDGES) { src = ei[e]; dst = ei[NUM_EDGES + e]; }
    else { src = e - NUM_EDGES; dst = e - NUM_EDGES; }
}

// ---------------- K1: h1 = x @ W1 via MFMA 16x16x32 bf16; fused logit dots ----------------
// Block: 64 rows x 64 cols, 4 waves; wave w = col-tile (cols w*16..+15 = heads 2w,2w+1).
// Fragment maps (HW-verified in guide): A[m=lane&15][k=quad*8+j], B[k=quad*8+j][n=lane&15],
// C/D col=lane&15, row=quad*4+reg.
// Barrier-free: A-fragments loaded DIRECT from global in fragment layout; no LDS at all.
__global__ __launch_bounds__(256) void gemm1_kernel(const float* __restrict__ x,
                                                    const float* __restrict__ W1,
                                                    const float* __restrict__ a_src,
                                                    const float* __restrict__ a_dst,
                                                    ushort* __restrict__ h1u,
                                                    float* __restrict__ als,
                                                    float* __restrict__ ald) {
    const int tid = threadIdx.x;
    const int wv = tid >> 6;            // wave = col-tile
    const int l = tid & 63;
    const int lm = l & 15;
    const int quad = l >> 4;
    const int r0 = blockIdx.x * 64;

    // B-fragments: this wave's 16-col slice of W1, all 8 K-chunks, in registers (32 VGPRs)
    bf16x8 bfrag[8];
#pragma unroll
    for (int kb = 0; kb < 8; kb++)
#pragma unroll
        for (int j = 0; j < 8; j++) {
            const int k = kb * 32 + quad * 8 + j;
            bfrag[kb][j] = (short)f32_to_bf16_rne(W1[k * D1 + wv * 16 + lm]);
        }

    f32x4 acc[4];
#pragma unroll
    for (int s = 0; s < 4; s++) acc[s] = (f32x4)(0.f);

    // per-lane A row pointers (fragment layout: row = lane&15 of each 16-row tile)
    const float* xp[4];
    bool rok[4];
#pragma unroll
    for (int s = 0; s < 4; s++) {
        const int row = r0 + s * 16 + lm;
        rok[s] = row < N_NODES;
        xp[s] = &x[(size_t)row * NFEAT + quad * 8];
    }

#pragma unroll
    for (int kb = 0; kb < 8; kb++) {
#pragma unroll
        for (int s = 0; s < 4; s++) {
            float4 va = make_float4(0.f, 0.f, 0.f, 0.f);
            float4 vb = make_float4(0.f, 0.f, 0.f, 0.f);
            if (rok[s]) {
                va = *(const float4*)(xp[s] + kb * 32);
                vb = *(const float4*)(xp[s] + kb * 32 + 4);
            }
            uint4 u;
            u.x = pack_bf16x2(va.x, va.y);
            u.y = pack_bf16x2(va.z, va.w);
            u.z = pack_bf16x2(vb.x, vb.y);
            u.w = pack_bf16x2(vb.z, vb.w);
            const bf16x8 af = *(const bf16x8*)&u;
            acc[s] = __builtin_amdgcn_mfma_f32_16x16x32_bf16(af, bfrag[kb], acc[s], 0, 0, 0);
        }
    }

    // epilogue: bf16 h1 stores + f32 logit dots (shfl over 8-lane head groups)
    const int head = wv * 2 + (lm >> 3);
    const int jc = l & 7;
    const float asl = a_src[head * NHID + jc];
    const float adl = a_dst[head * NHID + jc];
    const int col = wv * 16 + lm;
#pragma unroll
    for (int s = 0; s < 4; s++) {
#pragma unroll
        for (int r = 0; r < 4; r++) {
            const int row = r0 + s * 16 + quad * 4 + r;
            const float v = acc[s][r];
            float ps = v * asl, pd = v * adl;
            ps += __shfl_xor(ps, 1, 64); pd += __shfl_xor(pd, 1, 64);
            ps += __shfl_xor(ps, 2, 64); pd += __shfl_xor(pd, 2, 64);
            ps += __shfl_xor(ps, 4, 64); pd += __shfl_xor(pd, 4, 64);
            if (row < N_NODES) {
                h1u[(size_t)row * D1 + col] = (ushort)f32_to_bf16_rne(v);
                if (jc == 0) { als[row * HEADS + head] = ps; ald[row * HEADS + head] = pd; }
            }
        }
    }
}

// ---------------- K2: bin edges by dst bucket (LDS hist + chunk reservation) ----------------
// packed entry: (dst&255)<<20 | src   (src < 2^17)
__global__ __launch_bounds__(256) void bin_kernel(const int* __restrict__ ei,
                                                  int* __restrict__ bcur,
                                                  int* __restrict__ bin) {
    __shared__ int lcnt[NBUCK];
    __shared__ int lbase[NBUCK];
    const int tid = threadIdx.x;
    for (int b = tid; b < NBUCK; b += 256) lcnt[b] = 0;
    __syncthreads();
    const int e0 = blockIdx.x * BIN_EPB;
    int pk[BIN_EPT], bk[BIN_EPT], loff[BIN_EPT];
#pragma unroll
    for (int i = 0; i < BIN_EPT; i++) {
        const int e = e0 + i * 256 + tid;
        if (e < E_TOT) {
            int src, dst; edge_src_dst(ei, e, src, dst);
            bk[i] = dst >> BSHIFT;
            pk[i] = ((dst & 255) << 20) | src;
            loff[i] = atomicAdd(&lcnt[bk[i]], 1);
        } else bk[i] = -1;
    }
    __syncthreads();
    for (int b = tid; b < NBUCK; b += 256) {
        const int c = lcnt[b];
        lbase[b] = c ? atomicAdd(&bcur[b], c) : 0;
    }
    __syncthreads();
#pragma unroll
    for (int i = 0; i < BIN_EPT; i++) {
        if (bk[i] >= 0)
            bin[(size_t)bk[i] * BCAP + lbase[bk[i]] + loff[i]] = pk[i];
    }
}

// ---------------- K3: per-bucket LDS counting sort -> dst-sorted CSR ----------------
__global__ __launch_bounds__(256) void bsort_kernel(const int* __restrict__ bcur,
                                                    const int* __restrict__ bin,
                                                    int* __restrict__ csr,
                                                    int* __restrict__ row_ptr,
                                                    int* __restrict__ cnt) {
    __shared__ int hcnt[256];
    __shared__ int hpre[256];
    __shared__ int cur[256];
    __shared__ int ssrc[BCAP];   // 20 KB
    const int tid = threadIdx.x;
    const int bkt = blockIdx.x;
    const int cntb = bcur[bkt];
    const int base = bkt * BCAP;
    hcnt[tid] = 0;
    __syncthreads();
    for (int i = tid; i < cntb; i += 256)
        atomicAdd(&hcnt[bin[base + i] >> 20], 1);
    __syncthreads();
    const int myc = hcnt[tid];
    hpre[tid] = myc;
    __syncthreads();
    for (int off = 1; off < 256; off <<= 1) {
        const int t = (tid >= off) ? hpre[tid - off] : 0;
        __syncthreads();
        hpre[tid] += t;
        __syncthreads();
    }
    const int exc = hpre[tid] - myc;
    cur[tid] = exc;
    __syncthreads();
    for (int i = tid; i < cntb; i += 256) {
        const int v = bin[base + i];
        const int pos = atomicAdd(&cur[v >> 20], 1);
        ssrc[pos] = v & 0xFFFFF;
    }
    __syncthreads();
    for (int i = tid; i < cntb; i += 256) csr[base + i] = ssrc[i];
    const int n = (bkt << BSHIFT) + tid;
    if (n < N_NODES) { row_ptr[n] = base + exc; cnt[n] = myc; }
}

// ---------------- K4: gather layer 1 -- wave/node, 16 lanes x uint2 (4ch), 4 edge slots ----
// Software pipeline: csr index prefetched 2 iters ahead, als/h1b values 1 iter ahead,
// so the csr->value dependent-load chain spans a full loop body instead of serializing.
__global__ __launch_bounds__(256) void gather1_kernel(const int* __restrict__ row_ptr,
                                                      const int* __restrict__ cnt,
                                                      const int* __restrict__ csr_src,
                                                      const unsigned* __restrict__ h1b,
                                                      const float* __restrict__ als,
                                                      const float* __restrict__ ald,
                                                      float* __restrict__ out1) {
    const int tid = threadIdx.x;
    const int n = blockIdx.x * 4 + (tid >> 6);   // grid == N_NODES/4 exactly
    const int l = tid & 63;
    const int q = l >> 4;                        // edge slot 0..3
    const int c4 = l & 15;                       // channel quad: ch 4c4..4c4+3
    const int h = c4 >> 1;                       // head (all 4 channels in same head)
    const int start = row_ptr[n];
    const int deg = cnt[n];
    const float aldn = ald[n * HEADS + h];
    float a0 = 0.f, a1 = 0.f, a2 = 0.f, a3 = 0.f, wsum = 0.f;

    int i = q;
    float e0 = 0.f;
    uint2 u0 = make_uint2(0u, 0u);
    int sN = 0;
    if (i < deg) {
        const int s0 = csr_src[start + i];
        e0 = als[s0 * HEADS + h];
        u0 = *(const uint2*)&h1b[(size_t)s0 * 32 + c4 * 2];
    }
    if (i + 4 < deg) sN = csr_src[start + i + 4];

    for (; i < deg; i += 4) {
        int sNN = 0;
        if (i + 8 < deg) sNN = csr_src[start + i + 8];
        float e1 = 0.f;
        uint2 u1 = make_uint2(0u, 0u);
        if (i + 4 < deg) {
            e1 = als[sN * HEADS + h];
            u1 = *(const uint2*)&h1b[(size_t)sN * 32 + c4 * 2];
        }
        const float w = __expf(lrelu(e0 + aldn));
        const float2 hv0 = unpack_bf16x2(u0.x);
        const float2 hv1 = unpack_bf16x2(u0.y);
        a0 = fmaf(hv0.x, w, a0);
        a1 = fmaf(hv0.y, w, a1);
        a2 = fmaf(hv1.x, w, a2);
        a3 = fmaf(hv1.y, w, a3);
        wsum += w;
        e0 = e1; u0 = u1; sN = sNN;
    }

    // reduce across the 4 slots (16-lane groups)
    a0 += __shfl_down(a0, 32, 64);
    a1 += __shfl_down(a1, 32, 64);
    a2 += __shfl_down(a2, 32, 64);
    a3 += __shfl_down(a3, 32, 64);
    wsum += __shfl_down(wsum, 32, 64);
    a0 += __shfl_down(a0, 16, 64);
    a1 += __shfl_down(a1, 16, 64);
    a2 += __shfl_down(a2, 16, 64);
    a3 += __shfl_down(a3, 16, 64);
    wsum += __shfl_down(wsum, 16, 64);
    if (l < 16) {
        const float inv = 1.f / (wsum + 1e-16f);
        *(float4*)&out1[(size_t)n * D1 + c4 * 4] =
            make_float4(a0 * inv, a1 * inv, a2 * inv, a3 * inv);
    }
}

// ---------------- K5: z = elu(out1+b1); h2 = z @ W2 (bf16-packed); layer-2 logits ----------
__global__ __launch_bounds__(256) void layer2_node_kernel(const float* __restrict__ out1,
                                                          const float* __restrict__ b1,
                                                          const float* __restrict__ W2,
                                                          const float* __restrict__ a_src2,
                                                          const float* __restrict__ a_dst2,
                                                          unsigned* __restrict__ h2b,
                                                          float* __restrict__ als2,
                                                          float* __restrict__ ald2) {
    __shared__ float w2l[D1 * NCLASS];   // 8 KB
    __shared__ float b1l[D1];
    __shared__ float a2l[2 * NCLASS];
    const int tid = threadIdx.x;
    for (int i = tid; i < D1 * NCLASS; i += 256) w2l[i] = W2[i];
    if (tid < D1) b1l[tid] = b1[tid];
    if (tid < NCLASS) a2l[tid] = a_src2[tid];
    else if (tid < 2 * NCLASS) a2l[tid] = a_dst2[tid - NCLASS];
    __syncthreads();

    const int n = blockIdx.x * 256 + tid;
    if (n >= N_NODES) return;
    float acc[NCLASS];
#pragma unroll
    for (int c = 0; c < NCLASS; c++) acc[c] = 0.f;
    float as = 0.f, ad = 0.f;
    const float4* rp = (const float4*)&out1[(size_t)n * D1];
#pragma unroll 2
    for (int k4 = 0; k4 < 16; k4++) {
        const float4 v4 = rp[k4];
        const float vv[4] = {v4.x, v4.y, v4.z, v4.w};
#pragma unroll
        for (int j = 0; j < 4; j++) {
            const int k = k4 * 4 + j;
            float z = vv[j] + b1l[k];
            z = z > 0.f ? z : expm1f(z);   // jax.nn.elu
            const float* wr = &w2l[k * NCLASS];
#pragma unroll
            for (int c = 0; c < NCLASS; c++) acc[c] += z * wr[c];
        }
    }
#pragma unroll
    for (int c = 0; c < NCLASS; c++) { as += acc[c] * a2l[c]; ad += acc[c] * a2l[NCLASS + c]; }
#pragma unroll
    for (int q = 0; q < 4; q++) {
        uint4 pv;
        pv.x = pack_bf16x2(acc[q * 8 + 0], acc[q * 8 + 1]);
        pv.y = pack_bf16x2(acc[q * 8 + 2], acc[q * 8 + 3]);
        pv.z = pack_bf16x2(acc[q * 8 + 4], acc[q * 8 + 5]);
        pv.w = pack_bf16x2(acc[q * 8 + 6], acc[q * 8 + 7]);
        *(uint4*)&h2b[(size_t)n * 16 + q * 4] = pv;
    }
    als2[n] = as; ald2[n] = ad;
}

// ---------------- K6: gather layer 2 -- wave/node, 8 lanes x uint2 (4ch), 8 edge slots ----
__global__ __launch_bounds__(256) void gather2_kernel(const int* __restrict__ row_ptr,
                                                      const int* __restrict__ cnt,
                                                      const int* __restrict__ csr_src,
                                                      const unsigned* __restrict__ h2b,
                                                      const float* __restrict__ als2,
                                                      const float* __restrict__ ald2,
                                                      float* __restrict__ out2) {
    const int tid = threadIdx.x;
    const int n = blockIdx.x * 4 + (tid >> 6);   // grid == N_NODES/4 exactly
    const int l = tid & 63;
    const int q = l >> 3;                        // edge slot 0..7
    const int c4 = l & 7;                        // channel quad: ch 4c4..4c4+3
    const int start = row_ptr[n];
    const int deg = cnt[n];
    const float aldn = ald2[n];
    float a0 = 0.f, a1 = 0.f, a2 = 0.f, a3 = 0.f, wsum = 0.f;

    int i = q;
    float e0 = 0.f;
    uint2 u0 = make_uint2(0u, 0u);
    int sN = 0;
    if (i < deg) {
        const int s0 = csr_src[start + i];
        e0 = als2[s0];
        u0 = *(const uint2*)&h2b[(size_t)s0 * 16 + c4 * 2];
    }
    if (i + 8 < deg) sN = csr_src[start + i + 8];

    for (; i < deg; i += 8) {
        int sNN = 0;
        if (i + 16 < deg) sNN = csr_src[start + i + 16];
        float e1 = 0.f;
        uint2 u1 = make_uint2(0u, 0u);
        if (i + 8 < deg) {
            e1 = als2[sN];
            u1 = *(const uint2*)&h2b[(size_t)sN * 16 + c4 * 2];
        }
        const float w = __expf(lrelu(e0 + aldn));
        const float2 hv0 = unpack_bf16x2(u0.x);
        const float2 hv1 = unpack_bf16x2(u0.y);
        a0 = fmaf(hv0.x, w, a0);
        a1 = fmaf(hv0.y, w, a1);
        a2 = fmaf(hv1.x, w, a2);
        a3 = fmaf(hv1.y, w, a3);
        wsum += w;
        e0 = e1; u0 = u1; sN = sNN;
    }

    // reduce across the 8 slots (8-lane groups)
    a0 += __shfl_down(a0, 32, 64);
    a1 += __shfl_down(a1, 32, 64);
    a2 += __shfl_down(a2, 32, 64);
    a3 += __shfl_down(a3, 32, 64);
    wsum += __shfl_down(wsum, 32, 64);
    a0 += __shfl_down(a0, 16, 64);
    a1 += __shfl_down(a1, 16, 64);
    a2 += __shfl_down(a2, 16, 64);
    a3 += __shfl_down(a3, 16, 64);
    wsum += __shfl_down(wsum, 16, 64);
    a0 += __shfl_down(a0, 8, 64);
    a1 += __shfl_down(a1, 8, 64);
    a2 += __shfl_down(a2, 8, 64);
    a3 += __shfl_down(a3, 8, 64);
    wsum += __shfl_down(wsum, 8, 64);
    if (l < 8) {
        const float inv = 1.f / (wsum + 1e-16f);
        *(float4*)&out2[(size_t)n * NCLASS + c4 * 4] =
            make_float4(a0 * inv, a1 * inv, a2 * inv, a3 * inv);
    }
}

// ---------------- K7: + b2, log_softmax ----------------
__global__ __launch_bounds__(256) void logsoftmax_kernel(const float* __restrict__ out2,
                                                         const float* __restrict__ b2,
                                                         float* __restrict__ out) {
    __shared__ float b2l[NCLASS];
    if (threadIdx.x < NCLASS) b2l[threadIdx.x] = b2[threadIdx.x];
    __syncthreads();
    const int n = blockIdx.x * 256 + threadIdx.x;
    if (n >= N_NODES) return;
    float v[NCLASS];
    float mx = -INFINITY;
    const float4* rp = (const float4*)&out2[(size_t)n * NCLASS];
#pragma unroll
    for (int c4 = 0; c4 < NCLASS / 4; c4++) {
        const float4 t = rp[c4];
        v[c4 * 4 + 0] = t.x + b2l[c4 * 4 + 0];
        v[c4 * 4 + 1] = t.y + b2l[c4 * 4 + 1];
        v[c4 * 4 + 2] = t.z + b2l[c4 * 4 + 2];
        v[c4 * 4 + 3] = t.w + b2l[c4 * 4 + 3];
    }
#pragma unroll
    for (int c = 0; c < NCLASS; c++) mx = fmaxf(mx, v[c]);
    float s = 0.f;
#pragma unroll
    for (int c = 0; c < NCLASS; c++) s += __expf(v[c] - mx);
    const float lse = mx + logf(s);
    float4* op = (float4*)&out[(size_t)n * NCLASS];
#pragma unroll
    for (int c4 = 0; c4 < NCLASS / 4; c4++)
        op[c4] = make_float4(v[c4 * 4] - lse, v[c4 * 4 + 1] - lse, v[c4 * 4 + 2] - lse, v[c4 * 4 + 3] - lse);
}

extern "C" void kernel_launch(void* const* d_in, const int* in_sizes, int n_in,
                              void* d_out, int out_size, void* d_ws, size_t ws_size,
                              hipStream_t stream) {
    const float* x      = (const float*)d_in[0];
    const int*   ei     = (const int*)d_in[1];
    const float* W1     = (const float*)d_in[2];
    const float* a_src1 = (const float*)d_in[3];
    const float* a_dst1 = (const float*)d_in[4];
    const float* b1     = (const float*)d_in[5];
    const float* W2     = (const float*)d_in[6];
    const float* a_src2 = (const float*)d_in[7];
    const float* a_dst2 = (const float*)d_in[8];
    const float* b2     = (const float*)d_in[9];
    float* out = (float*)d_out;
    float* ws  = (float*)d_ws;

    ushort* h1u     = (ushort*)(ws + OFF_H1);
    unsigned* h1b   = (unsigned*)(ws + OFF_H1);
    float* out1     = ws + OFF_OUT1;
    float* als1     = ws + OFF_ALS1;
    float* ald1     = ws + OFF_ALD1;
    float* als2     = ws + OFF_ALS2;
    float* ald2     = ws + OFF_ALD2;
    int*   bcur     = (int*)(ws + OFF_BCUR);
    int*   row_ptr  = (int*)(ws + OFF_ROWP);
    int*   cnt      = (int*)(ws + OFF_CNT);
    int*   bin      = (int*)(ws + OFF_BIN);
    int*   csr      = (int*)(ws + OFF_CSR);
    unsigned* h2b   = (unsigned*)(ws + OFF_H1);          // alias: h1b dead after gather1
    float* out2     = ws + OFF_H1 + 3200000;             // beyond h2b's 1.6M uints

    hipMemsetAsync(bcur, 0, NBUCK * sizeof(int), stream);

    const int NB = (N_NODES + 255) / 256;   // 391

    gemm1_kernel<<<(N_NODES + 63) / 64, 256, 0, stream>>>(x, W1, a_src1, a_dst1, h1u, als1, ald1);
    bin_kernel<<<(E_TOT + BIN_EPB - 1) / BIN_EPB, 256, 0, stream>>>(ei, bcur, bin);
    bsort_kernel<<<NBUCK, 256, 0, stream>>>(bcur, bin, csr, row_ptr, cnt);
    gather1_kernel<<<N_NODES / 4, 256, 0, stream>>>(row_ptr, cnt, csr, h1b, als1, ald1, out1);
    layer2_node_kernel<<<NB, 256, 0, stream>>>(out1, b1, W2, a_src2, a_dst2, h2b, als2, ald2);
    gather2_kernel<<<N_NODES / 4, 256, 0, stream>>>(row_ptr, cnt, csr, h2b, als2, ald2, out2);
    logsoftmax_kernel<<<NB, 256, 0, stream>>>(out2, b2, out);
}

// Round 3
// 390.504 us; speedup vs baseline: 1.0081x; 1.0081x over previous
//
#include <hip/hip_runtime.h>
#include <math.h>

#define N_NODES 100000
#define NFEAT 256
#define D1 64          // HEADS*NHID
#define HEADS 8
#define NHID 8
#define NCLASS 32
#define NUM_EDGES 1600000
#define E_TOT 1700000  // + self loops
#define NEG_SLOPE 0.2f

// dst-bucketing: 256 nodes per bucket; CSR stored bucket-strided (no compaction)
#define BSHIFT 8
#define NBUCK 391            // ceil(100000/256)
#define BCAP 5120            // mean edges/bucket 4352, std ~66; +11.6 sigma headroom
#define BIN_EPB 4096
#define BIN_EPT 16

// LESSON (r4): wave-per-node x 25k waves >> block-per-bucket (TLP hides gather latency).
// LESSON (r9/polish): gather1 @76us was latency-bound (VALUBusy 56%, HBM 30%, VGPR 12,
// 0 conflicts -> nothing saturated). Fix = MLP: 4 edge slots x 16 lanes x uint2 loads
// + 2-deep csr / 1-deep value software pipeline. Same for gather2. WORKED (-20us).
// LESSON (r10): gemm1 @69us was barrier-bound (2x syncthreads/chunk, unprefetched load).
// LESSON (r11): barrier-free direct-load REGRESSED 69->80us: VGPR=60 means compiler kept
// ~2 loads in flight; chain global_load(L2 ~200cy)->pack->MFMA exposed per iteration.
// FETCH unchanged 50MB (L2 absorbed 4x wave redundancy fine). Fix = EXPLICIT register
// double-buffer (named pre[2][4][2], full unroll, static idx) + __launch_bounds__(256,3)
// so the ~130-VGPR working set fits: 8 loads/wave in flight, latency hides under pack+MFMA.

// ---- workspace layout (float offsets); h1/h2 are PACKED BF16 (uint = 2 ch) ----
#define OFF_H1    0            // h1b: 3.2M uints; reused: h2b=[0,1.6M) uints, out2=[3.2M,6.4M) f32
#define OFF_OUT1  6400000      // f32
#define OFF_ALS1  12800000
#define OFF_ALD1  13600000
#define OFF_ALS2  14400000
#define OFF_ALD2  14500000
#define OFF_BCUR  14600000     // 391 ints (pad to 1024)
#define OFF_ROWP  14601024
#define OFF_CNT   14701024
#define OFF_BIN   14801024     // 391*5120 ints (packed dl<<20|src)
#define OFF_CSR   16802944     // 391*5120 ints (dst-sorted src)

typedef __attribute__((ext_vector_type(8))) short bf16x8;
typedef __attribute__((ext_vector_type(4))) float f32x4;

__device__ __forceinline__ float lrelu(float x) { return x >= 0.f ? x : NEG_SLOPE * x; }

__device__ __forceinline__ unsigned f32_to_bf16_rne(float f) {
    unsigned u = __float_as_uint(f);
    return (u + 0x7fffu + ((u >> 16) & 1u)) >> 16;
}
__device__ __forceinline__ unsigned pack_bf16x2(float lo, float hi) {
    return f32_to_bf16_rne(lo) | (f32_to_bf16_rne(hi) << 16);
}
__device__ __forceinline__ float2 unpack_bf16x2(unsigned v) {
    return make_float2(__uint_as_float(v << 16), __uint_as_float(v & 0xffff0000u));
}

__device__ __forceinline__ void edge_src_dst(const int* __restrict__ ei, int e, int& src, int& dst) {
    if (e < NUM_EDGES) { src = ei[e]; dst = ei[NUM_EDGES + e]; }
    else { src = e - NUM_EDGES; dst = e - NUM_EDGES; }
}

// ---------------- K1: h1 = x @ W1 via MFMA 16x16x32 bf16; fused logit dots ----------------
// Block: 64 rows x 64 cols, 4 waves; wave w = col-tile (cols w*16..+15 = heads 2w,2w+1).
// Fragment maps (HW-verified in guide): A[m=lane&15][k=quad*8+j], B[k=quad*8+j][n=lane&15],
// C/D col=lane&15, row=quad*4+reg.
// Direct A-loads from global (L2-served across the block's 4 waves) + explicit 1-deep
// register double-buffer: 8x16B independent loads for chunk kb+1 fly while chunk kb packs+MFMAs.
__global__ __launch_bounds__(256, 3) void gemm1_kernel(const float* __restrict__ x,
                                                       const float* __restrict__ W1,
                                                       const float* __restrict__ a_src,
                                                       const float* __restrict__ a_dst,
                                                       ushort* __restrict__ h1u,
                                                       float* __restrict__ als,
                                                       float* __restrict__ ald) {
    const int tid = threadIdx.x;
    const int wv = tid >> 6;            // wave = col-tile
    const int l = tid & 63;
    const int lm = l & 15;
    const int quad = l >> 4;
    const int r0 = blockIdx.x * 64;

    // B-fragments: this wave's 16-col slice of W1, all 8 K-chunks, in registers (32 VGPRs)
    bf16x8 bfrag[8];
#pragma unroll
    for (int kb = 0; kb < 8; kb++)
#pragma unroll
        for (int j = 0; j < 8; j++) {
            const int k = kb * 32 + quad * 8 + j;
            bfrag[kb][j] = (short)f32_to_bf16_rne(W1[k * D1 + wv * 16 + lm]);
        }

    f32x4 acc[4];
#pragma unroll
    for (int s = 0; s < 4; s++) acc[s] = (f32x4)(0.f);

    // per-lane A row pointers (fragment layout: row = lane&15 of each 16-row tile).
    // Rows clamped (not zeroed): garbage rows compute garbage, never stored.
    const float* xp[4];
#pragma unroll
    for (int s = 0; s < 4; s++) {
        int row = r0 + s * 16 + lm;
        if (row >= N_NODES) row = N_NODES - 1;
        xp[s] = &x[(size_t)row * NFEAT + quad * 8];
    }

    // explicit register double-buffer; all indices compile-time under full unroll
    float4 pre[2][4][2];
#pragma unroll
    for (int s = 0; s < 4; s++) {
        pre[0][s][0] = *(const float4*)(xp[s] + 0);
        pre[0][s][1] = *(const float4*)(xp[s] + 4);
    }

#pragma unroll
    for (int kb = 0; kb < 8; kb++) {
        const int cur = kb & 1;
        const int nxt = cur ^ 1;
        if (kb < 7) {
#pragma unroll
            for (int s = 0; s < 4; s++) {
                pre[nxt][s][0] = *(const float4*)(xp[s] + (kb + 1) * 32);
                pre[nxt][s][1] = *(const float4*)(xp[s] + (kb + 1) * 32 + 4);
            }
        }
#pragma unroll
        for (int s = 0; s < 4; s++) {
            const float4 va = pre[cur][s][0];
            const float4 vb = pre[cur][s][1];
            uint4 u;
            u.x = pack_bf16x2(va.x, va.y);
            u.y = pack_bf16x2(va.z, va.w);
            u.z = pack_bf16x2(vb.x, vb.y);
            u.w = pack_bf16x2(vb.z, vb.w);
            const bf16x8 af = *(const bf16x8*)&u;
            acc[s] = __builtin_amdgcn_mfma_f32_16x16x32_bf16(af, bfrag[kb], acc[s], 0, 0, 0);
        }
    }

    // epilogue: bf16 h1 stores + f32 logit dots (shfl over 8-lane head groups)
    const int head = wv * 2 + (lm >> 3);
    const int jc = l & 7;
    const float asl = a_src[head * NHID + jc];
    const float adl = a_dst[head * NHID + jc];
    const int col = wv * 16 + lm;
#pragma unroll
    for (int s = 0; s < 4; s++) {
#pragma unroll
        for (int r = 0; r < 4; r++) {
            const int row = r0 + s * 16 + quad * 4 + r;
            const float v = acc[s][r];
            float ps = v * asl, pd = v * adl;
            ps += __shfl_xor(ps, 1, 64); pd += __shfl_xor(pd, 1, 64);
            ps += __shfl_xor(ps, 2, 64); pd += __shfl_xor(pd, 2, 64);
            ps += __shfl_xor(ps, 4, 64); pd += __shfl_xor(pd, 4, 64);
            if (row < N_NODES) {
                h1u[(size_t)row * D1 + col] = (ushort)f32_to_bf16_rne(v);
                if (jc == 0) { als[row * HEADS + head] = ps; ald[row * HEADS + head] = pd; }
            }
        }
    }
}

// ---------------- K2: bin edges by dst bucket (LDS hist + chunk reservation) ----------------
// packed entry: (dst&255)<<20 | src   (src < 2^17)
__global__ __launch_bounds__(256) void bin_kernel(const int* __restrict__ ei,
                                                  int* __restrict__ bcur,
                                                  int* __restrict__ bin) {
    __shared__ int lcnt[NBUCK];
    __shared__ int lbase[NBUCK];
    const int tid = threadIdx.x;
    for (int b = tid; b < NBUCK; b += 256) lcnt[b] = 0;
    __syncthreads();
    const int e0 = blockIdx.x * BIN_EPB;
    int pk[BIN_EPT], bk[BIN_EPT], loff[BIN_EPT];
#pragma unroll
    for (int i = 0; i < BIN_EPT; i++) {
        const int e = e0 + i * 256 + tid;
        if (e < E_TOT) {
            int src, dst; edge_src_dst(ei, e, src, dst);
            bk[i] = dst >> BSHIFT;
            pk[i] = ((dst & 255) << 20) | src;
            loff[i] = atomicAdd(&lcnt[bk[i]], 1);
        } else bk[i] = -1;
    }
    __syncthreads();
    for (int b = tid; b < NBUCK; b += 256) {
        const int c = lcnt[b];
        lbase[b] = c ? atomicAdd(&bcur[b], c) : 0;
    }
    __syncthreads();
#pragma unroll
    for (int i = 0; i < BIN_EPT; i++) {
        if (bk[i] >= 0)
            bin[(size_t)bk[i] * BCAP + lbase[bk[i]] + loff[i]] = pk[i];
    }
}

// ---------------- K3: per-bucket LDS counting sort -> dst-sorted CSR ----------------
__global__ __launch_bounds__(256) void bsort_kernel(const int* __restrict__ bcur,
                                                    const int* __restrict__ bin,
                                                    int* __restrict__ csr,
                                                    int* __restrict__ row_ptr,
                                                    int* __restrict__ cnt) {
    __shared__ int hcnt[256];
    __shared__ int hpre[256];
    __shared__ int cur[256];
    __shared__ int ssrc[BCAP];   // 20 KB
    const int tid = threadIdx.x;
    const int bkt = blockIdx.x;
    const int cntb = bcur[bkt];
    const int base = bkt * BCAP;
    hcnt[tid] = 0;
    __syncthreads();
    for (int i = tid; i < cntb; i += 256)
        atomicAdd(&hcnt[bin[base + i] >> 20], 1);
    __syncthreads();
    const int myc = hcnt[tid];
    hpre[tid] = myc;
    __syncthreads();
    for (int off = 1; off < 256; off <<= 1) {
        const int t = (tid >= off) ? hpre[tid - off] : 0;
        __syncthreads();
        hpre[tid] += t;
        __syncthreads();
    }
    const int exc = hpre[tid] - myc;
    cur[tid] = exc;
    __syncthreads();
    for (int i = tid; i < cntb; i += 256) {
        const int v = bin[base + i];
        const int pos = atomicAdd(&cur[v >> 20], 1);
        ssrc[pos] = v & 0xFFFFF;
    }
    __syncthreads();
    for (int i = tid; i < cntb; i += 256) csr[base + i] = ssrc[i];
    const int n = (bkt << BSHIFT) + tid;
    if (n < N_NODES) { row_ptr[n] = base + exc; cnt[n] = myc; }
}

// ---------------- K4: gather layer 1 -- wave/node, 16 lanes x uint2 (4ch), 4 edge slots ----
// Software pipeline: csr index prefetched 2 iters ahead, als/h1b values 1 iter ahead,
// so the csr->value dependent-load chain spans a full loop body instead of serializing.
__global__ __launch_bounds__(256) void gather1_kernel(const int* __restrict__ row_ptr,
                                                      const int* __restrict__ cnt,
                                                      const int* __restrict__ csr_src,
                                                      const unsigned* __restrict__ h1b,
                                                      const float* __restrict__ als,
                                                      const float* __restrict__ ald,
                                                      float* __restrict__ out1) {
    const int tid = threadIdx.x;
    const int n = blockIdx.x * 4 + (tid >> 6);   // grid == N_NODES/4 exactly
    const int l = tid & 63;
    const int q = l >> 4;                        // edge slot 0..3
    const int c4 = l & 15;                       // channel quad: ch 4c4..4c4+3
    const int h = c4 >> 1;                       // head (all 4 channels in same head)
    const int start = row_ptr[n];
    const int deg = cnt[n];
    const float aldn = ald[n * HEADS + h];
    float a0 = 0.f, a1 = 0.f, a2 = 0.f, a3 = 0.f, wsum = 0.f;

    int i = q;
    float e0 = 0.f;
    uint2 u0 = make_uint2(0u, 0u);
    int sN = 0;
    if (i < deg) {
        const int s0 = csr_src[start + i];
        e0 = als[s0 * HEADS + h];
        u0 = *(const uint2*)&h1b[(size_t)s0 * 32 + c4 * 2];
    }
    if (i + 4 < deg) sN = csr_src[start + i + 4];

    for (; i < deg; i += 4) {
        int sNN = 0;
        if (i + 8 < deg) sNN = csr_src[start + i + 8];
        float e1 = 0.f;
        uint2 u1 = make_uint2(0u, 0u);
        if (i + 4 < deg) {
            e1 = als[sN * HEADS + h];
            u1 = *(const uint2*)&h1b[(size_t)sN * 32 + c4 * 2];
        }
        const float w = __expf(lrelu(e0 + aldn));
        const float2 hv0 = unpack_bf16x2(u0.x);
        const float2 hv1 = unpack_bf16x2(u0.y);
        a0 = fmaf(hv0.x, w, a0);
        a1 = fmaf(hv0.y, w, a1);
        a2 = fmaf(hv1.x, w, a2);
        a3 = fmaf(hv1.y, w, a3);
        wsum += w;
        e0 = e1; u0 = u1; sN = sNN;
    }

    // reduce across the 4 slots (16-lane groups)
    a0 += __shfl_down(a0, 32, 64);
    a1 += __shfl_down(a1, 32, 64);
    a2 += __shfl_down(a2, 32, 64);
    a3 += __shfl_down(a3, 32, 64);
    wsum += __shfl_down(wsum, 32, 64);
    a0 += __shfl_down(a0, 16, 64);
    a1 += __shfl_down(a1, 16, 64);
    a2 += __shfl_down(a2, 16, 64);
    a3 += __shfl_down(a3, 16, 64);
    wsum += __shfl_down(wsum, 16, 64);
    if (l < 16) {
        const float inv = 1.f / (wsum + 1e-16f);
        *(float4*)&out1[(size_t)n * D1 + c4 * 4] =
            make_float4(a0 * inv, a1 * inv, a2 * inv, a3 * inv);
    }
}

// ---------------- K5: z = elu(out1+b1); h2 = z @ W2 (bf16-packed); layer-2 logits ----------
__global__ __launch_bounds__(256) void layer2_node_kernel(const float* __restrict__ out1,
                                                          const float* __restrict__ b1,
                                                          const float* __restrict__ W2,
                                                          const float* __restrict__ a_src2,
                                                          const float* __restrict__ a_dst2,
                                                          unsigned* __restrict__ h2b,
                                                          float* __restrict__ als2,
                                                          float* __restrict__ ald2) {
    __shared__ float w2l[D1 * NCLASS];   // 8 KB
    __shared__ float b1l[D1];
    __shared__ float a2l[2 * NCLASS];
    const int tid = threadIdx.x;
    for (int i = tid; i < D1 * NCLASS; i += 256) w2l[i] = W2[i];
    if (tid < D1) b1l[tid] = b1[tid];
    if (tid < NCLASS) a2l[tid] = a_src2[tid];
    else if (tid < 2 * NCLASS) a2l[tid] = a_dst2[tid - NCLASS];
    __syncthreads();

    const int n = blockIdx.x * 256 + tid;
    if (n >= N_NODES) return;
    float acc[NCLASS];
#pragma unroll
    for (int c = 0; c < NCLASS; c++) acc[c] = 0.f;
    float as = 0.f, ad = 0.f;
    const float4* rp = (const float4*)&out1[(size_t)n * D1];
#pragma unroll 2
    for (int k4 = 0; k4 < 16; k4++) {
        const float4 v4 = rp[k4];
        const float vv[4] = {v4.x, v4.y, v4.z, v4.w};
#pragma unroll
        for (int j = 0; j < 4; j++) {
            const int k = k4 * 4 + j;
            float z = vv[j] + b1l[k];
            z = z > 0.f ? z : expm1f(z);   // jax.nn.elu
            const float* wr = &w2l[k * NCLASS];
#pragma unroll
            for (int c = 0; c < NCLASS; c++) acc[c] += z * wr[c];
        }
    }
#pragma unroll
    for (int c = 0; c < NCLASS; c++) { as += acc[c] * a2l[c]; ad += acc[c] * a2l[NCLASS + c]; }
#pragma unroll
    for (int q = 0; q < 4; q++) {
        uint4 pv;
        pv.x = pack_bf16x2(acc[q * 8 + 0], acc[q * 8 + 1]);
        pv.y = pack_bf16x2(acc[q * 8 + 2], acc[q * 8 + 3]);
        pv.z = pack_bf16x2(acc[q * 8 + 4], acc[q * 8 + 5]);
        pv.w = pack_bf16x2(acc[q * 8 + 6], acc[q * 8 + 7]);
        *(uint4*)&h2b[(size_t)n * 16 + q * 4] = pv;
    }
    als2[n] = as; ald2[n] = ad;
}

// ---------------- K6: gather layer 2 -- wave/node, 8 lanes x uint2 (4ch), 8 edge slots ----
__global__ __launch_bounds__(256) void gather2_kernel(const int* __restrict__ row_ptr,
                                                      const int* __restrict__ cnt,
                                                      const int* __restrict__ csr_src,
                                                      const unsigned* __restrict__ h2b,
                                                      const float* __restrict__ als2,
                                                      const float* __restrict__ ald2,
                                                      float* __restrict__ out2) {
    const int tid = threadIdx.x;
    const int n = blockIdx.x * 4 + (tid >> 6);   // grid == N_NODES/4 exactly
    const int l = tid & 63;
    const int q = l >> 3;                        // edge slot 0..7
    const int c4 = l & 7;                        // channel quad: ch 4c4..4c4+3
    const int start = row_ptr[n];
    const int deg = cnt[n];
    const float aldn = ald2[n];
    float a0 = 0.f, a1 = 0.f, a2 = 0.f, a3 = 0.f, wsum = 0.f;

    int i = q;
    float e0 = 0.f;
    uint2 u0 = make_uint2(0u, 0u);
    int sN = 0;
    if (i < deg) {
        const int s0 = csr_src[start + i];
        e0 = als2[s0];
        u0 = *(const uint2*)&h2b[(size_t)s0 * 16 + c4 * 2];
    }
    if (i + 8 < deg) sN = csr_src[start + i + 8];

    for (; i < deg; i += 8) {
        int sNN = 0;
        if (i + 16 < deg) sNN = csr_src[start + i + 16];
        float e1 = 0.f;
        uint2 u1 = make_uint2(0u, 0u);
        if (i + 8 < deg) {
            e1 = als2[sN];
            u1 = *(const uint2*)&h2b[(size_t)sN * 16 + c4 * 2];
        }
        const float w = __expf(lrelu(e0 + aldn));
        const float2 hv0 = unpack_bf16x2(u0.x);
        const float2 hv1 = unpack_bf16x2(u0.y);
        a0 = fmaf(hv0.x, w, a0);
        a1 = fmaf(hv0.y, w, a1);
        a2 = fmaf(hv1.x, w, a2);
        a3 = fmaf(hv1.y, w, a3);
        wsum += w;
        e0 = e1; u0 = u1; sN = sNN;
    }

    // reduce across the 8 slots (8-lane groups)
    a0 += __shfl_down(a0, 32, 64);
    a1 += __shfl_down(a1, 32, 64);
    a2 += __shfl_down(a2, 32, 64);
    a3 += __shfl_down(a3, 32, 64);
    wsum += __shfl_down(wsum, 32, 64);
    a0 += __shfl_down(a0, 16, 64);
    a1 += __shfl_down(a1, 16, 64);
    a2 += __shfl_down(a2, 16, 64);
    a3 += __shfl_down(a3, 16, 64);
    wsum += __shfl_down(wsum, 16, 64);
    a0 += __shfl_down(a0, 8, 64);
    a1 += __shfl_down(a1, 8, 64);
    a2 += __shfl_down(a2, 8, 64);
    a3 += __shfl_down(a3, 8, 64);
    wsum += __shfl_down(wsum, 8, 64);
    if (l < 8) {
        const float inv = 1.f / (wsum + 1e-16f);
        *(float4*)&out2[(size_t)n * NCLASS + c4 * 4] =
            make_float4(a0 * inv, a1 * inv, a2 * inv, a3 * inv);
    }
}

// ---------------- K7: + b2, log_softmax ----------------
__global__ __launch_bounds__(256) void logsoftmax_kernel(const float* __restrict__ out2,
                                                         const float* __restrict__ b2,
                                                         float* __restrict__ out) {
    __shared__ float b2l[NCLASS];
    if (threadIdx.x < NCLASS) b2l[threadIdx.x] = b2[threadIdx.x];
    __syncthreads();
    const int n = blockIdx.x * 256 + threadIdx.x;
    if (n >= N_NODES) return;
    float v[NCLASS];
    float mx = -INFINITY;
    const float4* rp = (const float4*)&out2[(size_t)n * NCLASS];
#pragma unroll
    for (int c4 = 0; c4 < NCLASS / 4; c4++) {
        const float4 t = rp[c4];
        v[c4 * 4 + 0] = t.x + b2l[c4 * 4 + 0];
        v[c4 * 4 + 1] = t.y + b2l[c4 * 4 + 1];
        v[c4 * 4 + 2] = t.z + b2l[c4 * 4 + 2];
        v[c4 * 4 + 3] = t.w + b2l[c4 * 4 + 3];
    }
#pragma unroll
    for (int c = 0; c < NCLASS; c++) mx = fmaxf(mx, v[c]);
    float s = 0.f;
#pragma unroll
    for (int c = 0; c < NCLASS; c++) s += __expf(v[c] - mx);
    const float lse = mx + logf(s);
    float4* op = (float4*)&out[(size_t)n * NCLASS];
#pragma unroll
    for (int c4 = 0; c4 < NCLASS / 4; c4++)
        op[c4] = make_float4(v[c4 * 4] - lse, v[c4 * 4 + 1] - lse, v[c4 * 4 + 2] - lse, v[c4 * 4 + 3] - lse);
}

extern "C" void kernel_launch(void* const* d_in, const int* in_sizes, int n_in,
                              void* d_out, int out_size, void* d_ws, size_t ws_size,
                              hipStream_t stream) {
    const float* x      = (const float*)d_in[0];
    const int*   ei     = (const int*)d_in[1];
    const float* W1     = (const float*)d_in[2];
    const float* a_src1 = (const float*)d_in[3];
    const float* a_dst1 = (const float*)d_in[4];
    const float* b1     = (const float*)d_in[5];
    const float* W2     = (const float*)d_in[6];
    const float* a_src2 = (const float*)d_in[7];
    const float* a_dst2 = (const float*)d_in[8];
    const float* b2     = (const float*)d_in[9];
    float* out = (float*)d_out;
    float* ws  = (float*)d_ws;

    ushort* h1u     = (ushort*)(ws + OFF_H1);
    unsigned* h1b   = (unsigned*)(ws + OFF_H1);
    float* out1     = ws + OFF_OUT1;
    float* als1     = ws + OFF_ALS1;
    float* ald1     = ws + OFF_ALD1;
    float* als2     = ws + OFF_ALS2;
    float* ald2     = ws + OFF_ALD2;
    int*   bcur     = (int*)(ws + OFF_BCUR);
    int*   row_ptr  = (int*)(ws + OFF_ROWP);
    int*   cnt      = (int*)(ws + OFF_CNT);
    int*   bin      = (int*)(ws + OFF_BIN);
    int*   csr      = (int*)(ws + OFF_CSR);
    unsigned* h2b   = (unsigned*)(ws + OFF_H1);          // alias: h1b dead after gather1
    float* out2     = ws + OFF_H1 + 3200000;             // beyond h2b's 1.6M uints

    hipMemsetAsync(bcur, 0, NBUCK * sizeof(int), stream);

    const int NB = (N_NODES + 255) / 256;   // 391

    gemm1_kernel<<<(N_NODES + 63) / 64, 256, 0, stream>>>(x, W1, a_src1, a_dst1, h1u, als1, ald1);
    bin_kernel<<<(E_TOT + BIN_EPB - 1) / BIN_EPB, 256, 0, stream>>>(ei, bcur, bin);
    bsort_kernel<<<NBUCK, 256, 0, stream>>>(bcur, bin, csr, row_ptr, cnt);
    gather1_kernel<<<N_NODES / 4, 256, 0, stream>>>(row_ptr, cnt, csr, h1b, als1, ald1, out1);
    layer2_node_kernel<<<NB, 256, 0, stream>>>(out1, b1, W2, a_src2, a_dst2, h2b, als2, ald2);
    gather2_kernel<<<N_NODES / 4, 256, 0, stream>>>(row_ptr, cnt, csr, h2b, als2, ald2, out2);
    logsoftmax_kernel<<<NB, 256, 0, stream>>>(out2, b2, out);
}

// Round 4
// 367.397 us; speedup vs baseline: 1.0715x; 1.0629x over previous
//
#include <hip/hip_runtime.h>
#include <math.h>

#define N_NODES 100000
#define NFEAT 256
#define D1 64          // HEADS*NHID
#define HEADS 8
#define NHID 8
#define NCLASS 32
#define NUM_EDGES 1600000
#define E_TOT 1700000  // + self loops
#define NEG_SLOPE 0.2f

// dst-bucketing: 256 nodes per bucket; CSR stored bucket-strided (no compaction)
#define BSHIFT 8
#define NBUCK 391            // ceil(100000/256)
#define BCAP 5120            // mean edges/bucket 4352, std ~66; +11.6 sigma headroom
#define BIN_EPB 4096
#define BIN_EPT 16

// LESSON (r4): wave-per-node x 25k waves >> block-per-bucket (TLP hides gather latency).
// LESSON (r9/polish): gather MLP fix (4/8 edge slots + uint2 + 2-deep pipeline) WORKED (-20us).
// LESSON (r10): gemm1 @69us barrier-bound (load issued after compute, 2 barriers/chunk).
// LESSON (r11): barrier-free direct-load 80us — compiler serializes loads at VGPR=60.
// LESSON (r12): register double-buffer WITHOUT barriers is DEAD CODE to the scheduler:
// VGPR stayed 60, loads sunk to uses, dur unchanged. Lesson: source-level pipelining only
// sticks when a __syncthreads() sits between load-issue and use (compiler memory boundary).
// => v4: double-buffered LDS (2x5KB), prefetch chunk kb+1 into regs BEFORE MFMA(kb),
// pack+ds_write AFTER, ONE barrier per chunk. Global latency hides under MFMA+LDS phase.

// ---- workspace layout (float offsets); h1/h2 are PACKED BF16 (uint = 2 ch) ----
#define OFF_H1    0            // h1b: 3.2M uints; reused: h2b=[0,1.6M) uints, out2=[3.2M,6.4M) f32
#define OFF_OUT1  6400000      // f32
#define OFF_ALS1  12800000
#define OFF_ALD1  13600000
#define OFF_ALS2  14400000
#define OFF_ALD2  14500000
#define OFF_BCUR  14600000     // 391 ints (pad to 1024)
#define OFF_ROWP  14601024
#define OFF_CNT   14701024
#define OFF_BIN   14801024     // 391*5120 ints (packed dl<<20|src)
#define OFF_CSR   16802944     // 391*5120 ints (dst-sorted src)

typedef __attribute__((ext_vector_type(8))) short bf16x8;
typedef __attribute__((ext_vector_type(4))) float f32x4;

__device__ __forceinline__ float lrelu(float x) { return x >= 0.f ? x : NEG_SLOPE * x; }

__device__ __forceinline__ unsigned f32_to_bf16_rne(float f) {
    unsigned u = __float_as_uint(f);
    return (u + 0x7fffu + ((u >> 16) & 1u)) >> 16;
}
__device__ __forceinline__ unsigned pack_bf16x2(float lo, float hi) {
    return f32_to_bf16_rne(lo) | (f32_to_bf16_rne(hi) << 16);
}
__device__ __forceinline__ float2 unpack_bf16x2(unsigned v) {
    return make_float2(__uint_as_float(v << 16), __uint_as_float(v & 0xffff0000u));
}

__device__ __forceinline__ void edge_src_dst(const int* __restrict__ ei, int e, int& src, int& dst) {
    if (e < NUM_EDGES) { src = ei[e]; dst = ei[NUM_EDGES + e]; }
    else { src = e - NUM_EDGES; dst = e - NUM_EDGES; }
}

// ---------------- K1: h1 = x @ W1 via MFMA 16x16x32 bf16; fused logit dots ----------------
// Block: 64 rows x 64 cols, 4 waves; wave w = col-tile (cols w*16..+15 = heads 2w,2w+1).
// Fragment maps (HW-verified in guide): A[m=lane&15][k=quad*8+j], B[k=quad*8+j][n=lane&15],
// C/D col=lane&15, row=quad*4+reg.
// 2-phase pipeline: prefetch chunk kb+1 (regs) -> MFMA chunk kb (LDS buf[cur]) ->
// pack+write buf[nxt] -> ONE barrier. Barriers pin the issue order (r12 lesson).
__global__ __launch_bounds__(256) void gemm1_kernel(const float* __restrict__ x,
                                                    const float* __restrict__ W1,
                                                    const float* __restrict__ a_src,
                                                    const float* __restrict__ a_dst,
                                                    ushort* __restrict__ h1u,
                                                    float* __restrict__ als,
                                                    float* __restrict__ ald) {
    __shared__ unsigned xbf[2][64 * 20];   // double buffer: 64 rows x 32 bf16, stride 20 uints
    const int tid = threadIdx.x;
    const int wv = tid >> 6;            // wave = col-tile
    const int l = tid & 63;
    const int lm = l & 15;
    const int quad = l >> 4;
    const int r0 = blockIdx.x * 64;

    // B-fragments: this wave's 16-col slice of W1, all 8 K-chunks, in registers (32 VGPRs)
    bf16x8 bfrag[8];
#pragma unroll
    for (int kb = 0; kb < 8; kb++)
#pragma unroll
        for (int j = 0; j < 8; j++) {
            const int k = kb * 32 + quad * 8 + j;
            bfrag[kb][j] = (short)f32_to_bf16_rne(W1[k * D1 + wv * 16 + lm]);
        }

    f32x4 acc[4];
#pragma unroll
    for (int s = 0; s < 4; s++) acc[s] = (f32x4)(0.f);

    const int sr = tid >> 2;            // staging: row 0..63
    const int sk = (tid & 3) * 8;       // k-offset within 32-chunk
    const bool rok = (r0 + sr) < N_NODES;
    const float* xrow = &x[(size_t)(r0 + sr) * NFEAT];
    const int swrd = sr * 20 + (tid & 3) * 4;   // LDS write word offset

    // prologue: load + pack + write chunk 0 into buf 0
    {
        uint4 pv = make_uint4(0, 0, 0, 0);
        if (rok) {
            const float4 va = *(const float4*)&xrow[sk];
            const float4 vb = *(const float4*)&xrow[sk + 4];
            pv.x = pack_bf16x2(va.x, va.y);
            pv.y = pack_bf16x2(va.z, va.w);
            pv.z = pack_bf16x2(vb.x, vb.y);
            pv.w = pack_bf16x2(vb.z, vb.w);
        }
        *(uint4*)&xbf[0][swrd] = pv;
    }
    __syncthreads();

#pragma unroll
    for (int kb = 0; kb < 8; kb++) {
        const int cur = kb & 1;
        const int nxt = cur ^ 1;
        // issue next chunk's global loads (in flight during the MFMA phase below;
        // the barrier between issue and use pins this order against the scheduler)
        float4 na = make_float4(0.f, 0.f, 0.f, 0.f);
        float4 nb = make_float4(0.f, 0.f, 0.f, 0.f);
        if (kb < 7 && rok) {
            na = *(const float4*)&xrow[(kb + 1) * 32 + sk];
            nb = *(const float4*)&xrow[(kb + 1) * 32 + sk + 4];
        }
        // MFMA phase: consume buf[cur]
#pragma unroll
        for (int s = 0; s < 4; s++) {
            const uint4 u = *(const uint4*)&xbf[cur][(s * 16 + lm) * 20 + quad * 4];
            const bf16x8 af = *(const bf16x8*)&u;
            acc[s] = __builtin_amdgcn_mfma_f32_16x16x32_bf16(af, bfrag[kb], acc[s], 0, 0, 0);
        }
        // pack + write next chunk into the other buffer (no reader conflict), one barrier
        if (kb < 7) {
            uint4 pv;
            pv.x = pack_bf16x2(na.x, na.y);
            pv.y = pack_bf16x2(na.z, na.w);
            pv.z = pack_bf16x2(nb.x, nb.y);
            pv.w = pack_bf16x2(nb.z, nb.w);
            *(uint4*)&xbf[nxt][swrd] = pv;
            __syncthreads();
        }
    }

    // epilogue: bf16 h1 stores + f32 logit dots (shfl over 8-lane head groups)
    const int head = wv * 2 + (lm >> 3);
    const int jc = l & 7;
    const float asl = a_src[head * NHID + jc];
    const float adl = a_dst[head * NHID + jc];
    const int col = wv * 16 + lm;
#pragma unroll
    for (int s = 0; s < 4; s++) {
#pragma unroll
        for (int r = 0; r < 4; r++) {
            const int row = r0 + s * 16 + quad * 4 + r;
            const float v = acc[s][r];
            float ps = v * asl, pd = v * adl;
            ps += __shfl_xor(ps, 1, 64); pd += __shfl_xor(pd, 1, 64);
            ps += __shfl_xor(ps, 2, 64); pd += __shfl_xor(pd, 2, 64);
            ps += __shfl_xor(ps, 4, 64); pd += __shfl_xor(pd, 4, 64);
            if (row < N_NODES) {
                h1u[(size_t)row * D1 + col] = (ushort)f32_to_bf16_rne(v);
                if (jc == 0) { als[row * HEADS + head] = ps; ald[row * HEADS + head] = pd; }
            }
        }
    }
}

// ---------------- K2: bin edges by dst bucket (LDS hist + chunk reservation) ----------------
// packed entry: (dst&255)<<20 | src   (src < 2^17)
__global__ __launch_bounds__(256) void bin_kernel(const int* __restrict__ ei,
                                                  int* __restrict__ bcur,
                                                  int* __restrict__ bin) {
    __shared__ int lcnt[NBUCK];
    __shared__ int lbase[NBUCK];
    const int tid = threadIdx.x;
    for (int b = tid; b < NBUCK; b += 256) lcnt[b] = 0;
    __syncthreads();
    const int e0 = blockIdx.x * BIN_EPB;
    int pk[BIN_EPT], bk[BIN_EPT], loff[BIN_EPT];
#pragma unroll
    for (int i = 0; i < BIN_EPT; i++) {
        const int e = e0 + i * 256 + tid;
        if (e < E_TOT) {
            int src, dst; edge_src_dst(ei, e, src, dst);
            bk[i] = dst >> BSHIFT;
            pk[i] = ((dst & 255) << 20) | src;
            loff[i] = atomicAdd(&lcnt[bk[i]], 1);
        } else bk[i] = -1;
    }
    __syncthreads();
    for (int b = tid; b < NBUCK; b += 256) {
        const int c = lcnt[b];
        lbase[b] = c ? atomicAdd(&bcur[b], c) : 0;
    }
    __syncthreads();
#pragma unroll
    for (int i = 0; i < BIN_EPT; i++) {
        if (bk[i] >= 0)
            bin[(size_t)bk[i] * BCAP + lbase[bk[i]] + loff[i]] = pk[i];
    }
}

// ---------------- K3: per-bucket LDS counting sort -> dst-sorted CSR ----------------
__global__ __launch_bounds__(256) void bsort_kernel(const int* __restrict__ bcur,
                                                    const int* __restrict__ bin,
                                                    int* __restrict__ csr,
                                                    int* __restrict__ row_ptr,
                                                    int* __restrict__ cnt) {
    __shared__ int hcnt[256];
    __shared__ int hpre[256];
    __shared__ int cur[256];
    __shared__ int ssrc[BCAP];   // 20 KB
    const int tid = threadIdx.x;
    const int bkt = blockIdx.x;
    const int cntb = bcur[bkt];
    const int base = bkt * BCAP;
    hcnt[tid] = 0;
    __syncthreads();
    for (int i = tid; i < cntb; i += 256)
        atomicAdd(&hcnt[bin[base + i] >> 20], 1);
    __syncthreads();
    const int myc = hcnt[tid];
    hpre[tid] = myc;
    __syncthreads();
    for (int off = 1; off < 256; off <<= 1) {
        const int t = (tid >= off) ? hpre[tid - off] : 0;
        __syncthreads();
        hpre[tid] += t;
        __syncthreads();
    }
    const int exc = hpre[tid] - myc;
    cur[tid] = exc;
    __syncthreads();
    for (int i = tid; i < cntb; i += 256) {
        const int v = bin[base + i];
        const int pos = atomicAdd(&cur[v >> 20], 1);
        ssrc[pos] = v & 0xFFFFF;
    }
    __syncthreads();
    for (int i = tid; i < cntb; i += 256) csr[base + i] = ssrc[i];
    const int n = (bkt << BSHIFT) + tid;
    if (n < N_NODES) { row_ptr[n] = base + exc; cnt[n] = myc; }
}

// ---------------- K4: gather layer 1 -- wave/node, 16 lanes x uint2 (4ch), 4 edge slots ----
// Software pipeline: csr index prefetched 2 iters ahead, als/h1b values 1 iter ahead,
// so the csr->value dependent-load chain spans a full loop body instead of serializing.
__global__ __launch_bounds__(256) void gather1_kernel(const int* __restrict__ row_ptr,
                                                      const int* __restrict__ cnt,
                                                      const int* __restrict__ csr_src,
                                                      const unsigned* __restrict__ h1b,
                                                      const float* __restrict__ als,
                                                      const float* __restrict__ ald,
                                                      float* __restrict__ out1) {
    const int tid = threadIdx.x;
    const int n = blockIdx.x * 4 + (tid >> 6);   // grid == N_NODES/4 exactly
    const int l = tid & 63;
    const int q = l >> 4;                        // edge slot 0..3
    const int c4 = l & 15;                       // channel quad: ch 4c4..4c4+3
    const int h = c4 >> 1;                       // head (all 4 channels in same head)
    const int start = row_ptr[n];
    const int deg = cnt[n];
    const float aldn = ald[n * HEADS + h];
    float a0 = 0.f, a1 = 0.f, a2 = 0.f, a3 = 0.f, wsum = 0.f;

    int i = q;
    float e0 = 0.f;
    uint2 u0 = make_uint2(0u, 0u);
    int sN = 0;
    if (i < deg) {
        const int s0 = csr_src[start + i];
        e0 = als[s0 * HEADS + h];
        u0 = *(const uint2*)&h1b[(size_t)s0 * 32 + c4 * 2];
    }
    if (i + 4 < deg) sN = csr_src[start + i + 4];

    for (; i < deg; i += 4) {
        int sNN = 0;
        if (i + 8 < deg) sNN = csr_src[start + i + 8];
        float e1 = 0.f;
        uint2 u1 = make_uint2(0u, 0u);
        if (i + 4 < deg) {
            e1 = als[sN * HEADS + h];
            u1 = *(const uint2*)&h1b[(size_t)sN * 32 + c4 * 2];
        }
        const float w = __expf(lrelu(e0 + aldn));
        const float2 hv0 = unpack_bf16x2(u0.x);
        const float2 hv1 = unpack_bf16x2(u0.y);
        a0 = fmaf(hv0.x, w, a0);
        a1 = fmaf(hv0.y, w, a1);
        a2 = fmaf(hv1.x, w, a2);
        a3 = fmaf(hv1.y, w, a3);
        wsum += w;
        e0 = e1; u0 = u1; sN = sNN;
    }

    // reduce across the 4 slots (16-lane groups)
    a0 += __shfl_down(a0, 32, 64);
    a1 += __shfl_down(a1, 32, 64);
    a2 += __shfl_down(a2, 32, 64);
    a3 += __shfl_down(a3, 32, 64);
    wsum += __shfl_down(wsum, 32, 64);
    a0 += __shfl_down(a0, 16, 64);
    a1 += __shfl_down(a1, 16, 64);
    a2 += __shfl_down(a2, 16, 64);
    a3 += __shfl_down(a3, 16, 64);
    wsum += __shfl_down(wsum, 16, 64);
    if (l < 16) {
        const float inv = 1.f / (wsum + 1e-16f);
        *(float4*)&out1[(size_t)n * D1 + c4 * 4] =
            make_float4(a0 * inv, a1 * inv, a2 * inv, a3 * inv);
    }
}

// ---------------- K5: z = elu(out1+b1); h2 = z @ W2 (bf16-packed); layer-2 logits ----------
__global__ __launch_bounds__(256) void layer2_node_kernel(const float* __restrict__ out1,
                                                          const float* __restrict__ b1,
                                                          const float* __restrict__ W2,
                                                          const float* __restrict__ a_src2,
                                                          const float* __restrict__ a_dst2,
                                                          unsigned* __restrict__ h2b,
                                                          float* __restrict__ als2,
                                                          float* __restrict__ ald2) {
    __shared__ float w2l[D1 * NCLASS];   // 8 KB
    __shared__ float b1l[D1];
    __shared__ float a2l[2 * NCLASS];
    const int tid = threadIdx.x;
    for (int i = tid; i < D1 * NCLASS; i += 256) w2l[i] = W2[i];
    if (tid < D1) b1l[tid] = b1[tid];
    if (tid < NCLASS) a2l[tid] = a_src2[tid];
    else if (tid < 2 * NCLASS) a2l[tid] = a_dst2[tid - NCLASS];
    __syncthreads();

    const int n = blockIdx.x * 256 + tid;
    if (n >= N_NODES) return;
    float acc[NCLASS];
#pragma unroll
    for (int c = 0; c < NCLASS; c++) acc[c] = 0.f;
    float as = 0.f, ad = 0.f;
    const float4* rp = (const float4*)&out1[(size_t)n * D1];
#pragma unroll 2
    for (int k4 = 0; k4 < 16; k4++) {
        const float4 v4 = rp[k4];
        const float vv[4] = {v4.x, v4.y, v4.z, v4.w};
#pragma unroll
        for (int j = 0; j < 4; j++) {
            const int k = k4 * 4 + j;
            float z = vv[j] + b1l[k];
            z = z > 0.f ? z : expm1f(z);   // jax.nn.elu
            const float* wr = &w2l[k * NCLASS];
#pragma unroll
            for (int c = 0; c < NCLASS; c++) acc[c] += z * wr[c];
        }
    }
#pragma unroll
    for (int c = 0; c < NCLASS; c++) { as += acc[c] * a2l[c]; ad += acc[c] * a2l[NCLASS + c]; }
#pragma unroll
    for (int q = 0; q < 4; q++) {
        uint4 pv;
        pv.x = pack_bf16x2(acc[q * 8 + 0], acc[q * 8 + 1]);
        pv.y = pack_bf16x2(acc[q * 8 + 2], acc[q * 8 + 3]);
        pv.z = pack_bf16x2(acc[q * 8 + 4], acc[q * 8 + 5]);
        pv.w = pack_bf16x2(acc[q * 8 + 6], acc[q * 8 + 7]);
        *(uint4*)&h2b[(size_t)n * 16 + q * 4] = pv;
    }
    als2[n] = as; ald2[n] = ad;
}

// ---------------- K6: gather layer 2 -- wave/node, 8 lanes x uint2 (4ch), 8 edge slots ----
__global__ __launch_bounds__(256) void gather2_kernel(const int* __restrict__ row_ptr,
                                                      const int* __restrict__ cnt,
                                                      const int* __restrict__ csr_src,
                                                      const unsigned* __restrict__ h2b,
                                                      const float* __restrict__ als2,
                                                      const float* __restrict__ ald2,
                                                      float* __restrict__ out2) {
    const int tid = threadIdx.x;
    const int n = blockIdx.x * 4 + (tid >> 6);   // grid == N_NODES/4 exactly
    const int l = tid & 63;
    const int q = l >> 3;                        // edge slot 0..7
    const int c4 = l & 7;                        // channel quad: ch 4c4..4c4+3
    const int start = row_ptr[n];
    const int deg = cnt[n];
    const float aldn = ald2[n];
    float a0 = 0.f, a1 = 0.f, a2 = 0.f, a3 = 0.f, wsum = 0.f;

    int i = q;
    float e0 = 0.f;
    uint2 u0 = make_uint2(0u, 0u);
    int sN = 0;
    if (i < deg) {
        const int s0 = csr_src[start + i];
        e0 = als2[s0];
        u0 = *(const uint2*)&h2b[(size_t)s0 * 16 + c4 * 2];
    }
    if (i + 8 < deg) sN = csr_src[start + i + 8];

    for (; i < deg; i += 8) {
        int sNN = 0;
        if (i + 16 < deg) sNN = csr_src[start + i + 16];
        float e1 = 0.f;
        uint2 u1 = make_uint2(0u, 0u);
        if (i + 8 < deg) {
            e1 = als2[sN];
            u1 = *(const uint2*)&h2b[(size_t)sN * 16 + c4 * 2];
        }
        const float w = __expf(lrelu(e0 + aldn));
        const float2 hv0 = unpack_bf16x2(u0.x);
        const float2 hv1 = unpack_bf16x2(u0.y);
        a0 = fmaf(hv0.x, w, a0);
        a1 = fmaf(hv0.y, w, a1);
        a2 = fmaf(hv1.x, w, a2);
        a3 = fmaf(hv1.y, w, a3);
        wsum += w;
        e0 = e1; u0 = u1; sN = sNN;
    }

    // reduce across the 8 slots (8-lane groups)
    a0 += __shfl_down(a0, 32, 64);
    a1 += __shfl_down(a1, 32, 64);
    a2 += __shfl_down(a2, 32, 64);
    a3 += __shfl_down(a3, 32, 64);
    wsum += __shfl_down(wsum, 32, 64);
    a0 += __shfl_down(a0, 16, 64);
    a1 += __shfl_down(a1, 16, 64);
    a2 += __shfl_down(a2, 16, 64);
    a3 += __shfl_down(a3, 16, 64);
    wsum += __shfl_down(wsum, 16, 64);
    a0 += __shfl_down(a0, 8, 64);
    a1 += __shfl_down(a1, 8, 64);
    a2 += __shfl_down(a2, 8, 64);
    a3 += __shfl_down(a3, 8, 64);
    wsum += __shfl_down(wsum, 8, 64);
    if (l < 8) {
        const float inv = 1.f / (wsum + 1e-16f);
        *(float4*)&out2[(size_t)n * NCLASS + c4 * 4] =
            make_float4(a0 * inv, a1 * inv, a2 * inv, a3 * inv);
    }
}

// ---------------- K7: + b2, log_softmax ----------------
__global__ __launch_bounds__(256) void logsoftmax_kernel(const float* __restrict__ out2,
                                                         const float* __restrict__ b2,
                                                         float* __restrict__ out) {
    __shared__ float b2l[NCLASS];
    if (threadIdx.x < NCLASS) b2l[threadIdx.x] = b2[threadIdx.x];
    __syncthreads();
    const int n = blockIdx.x * 256 + threadIdx.x;
    if (n >= N_NODES) return;
    float v[NCLASS];
    float mx = -INFINITY;
    const float4* rp = (const float4*)&out2[(size_t)n * NCLASS];
#pragma unroll
    for (int c4 = 0; c4 < NCLASS / 4; c4++) {
        const float4 t = rp[c4];
        v[c4 * 4 + 0] = t.x + b2l[c4 * 4 + 0];
        v[c4 * 4 + 1] = t.y + b2l[c4 * 4 + 1];
        v[c4 * 4 + 2] = t.z + b2l[c4 * 4 + 2];
        v[c4 * 4 + 3] = t.w + b2l[c4 * 4 + 3];
    }
#pragma unroll
    for (int c = 0; c < NCLASS; c++) mx = fmaxf(mx, v[c]);
    float s = 0.f;
#pragma unroll
    for (int c = 0; c < NCLASS; c++) s += __expf(v[c] - mx);
    const float lse = mx + logf(s);
    float4* op = (float4*)&out[(size_t)n * NCLASS];
#pragma unroll
    for (int c4 = 0; c4 < NCLASS / 4; c4++)
        op[c4] = make_float4(v[c4 * 4] - lse, v[c4 * 4 + 1] - lse, v[c4 * 4 + 2] - lse, v[c4 * 4 + 3] - lse);
}

extern "C" void kernel_launch(void* const* d_in, const int* in_sizes, int n_in,
                              void* d_out, int out_size, void* d_ws, size_t ws_size,
                              hipStream_t stream) {
    const float* x      = (const float*)d_in[0];
    const int*   ei     = (const int*)d_in[1];
    const float* W1     = (const float*)d_in[2];
    const float* a_src1 = (const float*)d_in[3];
    const float* a_dst1 = (const float*)d_in[4];
    const float* b1     = (const float*)d_in[5];
    const float* W2     = (const float*)d_in[6];
    const float* a_src2 = (const float*)d_in[7];
    const float* a_dst2 = (const float*)d_in[8];
    const float* b2     = (const float*)d_in[9];
    float* out = (float*)d_out;
    float* ws  = (float*)d_ws;

    ushort* h1u     = (ushort*)(ws + OFF_H1);
    unsigned* h1b   = (unsigned*)(ws + OFF_H1);
    float* out1     = ws + OFF_OUT1;
    float* als1     = ws + OFF_ALS1;
    float* ald1     = ws + OFF_ALD1;
    float* als2     = ws + OFF_ALS2;
    float* ald2     = ws + OFF_ALD2;
    int*   bcur     = (int*)(ws + OFF_BCUR);
    int*   row_ptr  = (int*)(ws + OFF_ROWP);
    int*   cnt      = (int*)(ws + OFF_CNT);
    int*   bin      = (int*)(ws + OFF_BIN);
    int*   csr      = (int*)(ws + OFF_CSR);
    unsigned* h2b   = (unsigned*)(ws + OFF_H1);          // alias: h1b dead after gather1
    float* out2     = ws + OFF_H1 + 3200000;             // beyond h2b's 1.6M uints

    hipMemsetAsync(bcur, 0, NBUCK * sizeof(int), stream);

    const int NB = (N_NODES + 255) / 256;   // 391

    gemm1_kernel<<<(N_NODES + 63) / 64, 256, 0, stream>>>(x, W1, a_src1, a_dst1, h1u, als1, ald1);
    bin_kernel<<<(E_TOT + BIN_EPB - 1) / BIN_EPB, 256, 0, stream>>>(ei, bcur, bin);
    bsort_kernel<<<NBUCK, 256, 0, stream>>>(bcur, bin, csr, row_ptr, cnt);
    gather1_kernel<<<N_NODES / 4, 256, 0, stream>>>(row_ptr, cnt, csr, h1b, als1, ald1, out1);
    layer2_node_kernel<<<NB, 256, 0, stream>>>(out1, b1, W2, a_src2, a_dst2, h2b, als2, ald2);
    gather2_kernel<<<N_NODES / 4, 256, 0, stream>>>(row_ptr, cnt, csr, h2b, als2, ald2, out2);
    logsoftmax_kernel<<<NB, 256, 0, stream>>>(out2, b2, out);
}

// Round 6
// 357.011 us; speedup vs baseline: 1.1026x; 1.0291x over previous
//
#include <hip/hip_runtime.h>
#include <math.h>

#define N_NODES 100000
#define NFEAT 256
#define D1 64          // HEADS*NHID
#define HEADS 8
#define NHID 8
#define NCLASS 32
#define NUM_EDGES 1600000
#define E_TOT 1700000  // + self loops
#define NEG_SLOPE 0.2f

// dst-bucketing: 256 nodes per bucket; CSR stored bucket-strided (no compaction)
#define BSHIFT 8
#define NBUCK 391            // ceil(100000/256)
#define BCAP 5120            // mean edges/bucket 4352, std ~66; +11.6 sigma headroom
#define BIN_EPB 4096
#define BIN_EPT 16

// LESSON (r4): wave-per-node x 25k waves >> block-per-bucket (TLP hides gather latency).
// LESSON (r9): gather MLP fix (edge slots + vector loads + pipeline) 76->63us.
// LESSON (r10-r13): gemm1 — barrier-free variants stuck at 77-80us (compiler sinks
// prefetch loads to uses when no barrier pins them, VGPR stays 60); LDS double-buffer
// + ONE barrier per chunk + reg prefetch across the barrier WORKED (out of top-5).
// Source-level pipelining only sticks when __syncthreads() sits between issue and use.
// LESSON (r14): gather1 @63us still latency-bound (HBM 36%, VALU 59%, VGPR 16!).
// More MLP: 8 slots x 8 lanes x uint4 (lane = head octet, kills redundant exp),
// 2-deep value pipeline (16 h1b loads in flight/wave). gather2: 16 slots x 4 lanes.
// NOTE (r15): r14's bench was an infra failure (container acquisition), not a kernel
// failure — source re-audited (guards exact, alignment ok, no new sync) and resubmitted.

// ---- workspace layout (float offsets); h1/h2 are PACKED BF16 (uint = 2 ch) ----
#define OFF_H1    0            // h1b: 3.2M uints; reused: h2b=[0,1.6M) uints, out2=[3.2M,6.4M) f32
#define OFF_OUT1  6400000      // f32
#define OFF_ALS1  12800000
#define OFF_ALD1  13600000
#define OFF_ALS2  14400000
#define OFF_ALD2  14500000
#define OFF_BCUR  14600000     // 391 ints (pad to 1024)
#define OFF_ROWP  14601024
#define OFF_CNT   14701024
#define OFF_BIN   14801024     // 391*5120 ints (packed dl<<20|src)
#define OFF_CSR   16802944     // 391*5120 ints (dst-sorted src)

typedef __attribute__((ext_vector_type(8))) short bf16x8;
typedef __attribute__((ext_vector_type(4))) float f32x4;

__device__ __forceinline__ float lrelu(float x) { return x >= 0.f ? x : NEG_SLOPE * x; }

__device__ __forceinline__ unsigned f32_to_bf16_rne(float f) {
    unsigned u = __float_as_uint(f);
    return (u + 0x7fffu + ((u >> 16) & 1u)) >> 16;
}
__device__ __forceinline__ unsigned pack_bf16x2(float lo, float hi) {
    return f32_to_bf16_rne(lo) | (f32_to_bf16_rne(hi) << 16);
}
__device__ __forceinline__ float2 unpack_bf16x2(unsigned v) {
    return make_float2(__uint_as_float(v << 16), __uint_as_float(v & 0xffff0000u));
}

__device__ __forceinline__ void edge_src_dst(const int* __restrict__ ei, int e, int& src, int& dst) {
    if (e < NUM_EDGES) { src = ei[e]; dst = ei[NUM_EDGES + e]; }
    else { src = e - NUM_EDGES; dst = e - NUM_EDGES; }
}

// ---------------- K1: h1 = x @ W1 via MFMA 16x16x32 bf16; fused logit dots ----------------
// Block: 64 rows x 64 cols, 4 waves; wave w = col-tile (cols w*16..+15 = heads 2w,2w+1).
// Fragment maps (HW-verified in guide): A[m=lane&15][k=quad*8+j], B[k=quad*8+j][n=lane&15],
// C/D col=lane&15, row=quad*4+reg.
// 2-phase pipeline: prefetch chunk kb+1 (regs) -> MFMA chunk kb (LDS buf[cur]) ->
// pack+write buf[nxt] -> ONE barrier. Barriers pin the issue order (r12 lesson).
__global__ __launch_bounds__(256) void gemm1_kernel(const float* __restrict__ x,
                                                    const float* __restrict__ W1,
                                                    const float* __restrict__ a_src,
                                                    const float* __restrict__ a_dst,
                                                    ushort* __restrict__ h1u,
                                                    float* __restrict__ als,
                                                    float* __restrict__ ald) {
    __shared__ unsigned xbf[2][64 * 20];   // double buffer: 64 rows x 32 bf16, stride 20 uints
    const int tid = threadIdx.x;
    const int wv = tid >> 6;            // wave = col-tile
    const int l = tid & 63;
    const int lm = l & 15;
    const int quad = l >> 4;
    const int r0 = blockIdx.x * 64;

    // B-fragments: this wave's 16-col slice of W1, all 8 K-chunks, in registers (32 VGPRs)
    bf16x8 bfrag[8];
#pragma unroll
    for (int kb = 0; kb < 8; kb++)
#pragma unroll
        for (int j = 0; j < 8; j++) {
            const int k = kb * 32 + quad * 8 + j;
            bfrag[kb][j] = (short)f32_to_bf16_rne(W1[k * D1 + wv * 16 + lm]);
        }

    f32x4 acc[4];
#pragma unroll
    for (int s = 0; s < 4; s++) acc[s] = (f32x4)(0.f);

    const int sr = tid >> 2;            // staging: row 0..63
    const int sk = (tid & 3) * 8;       // k-offset within 32-chunk
    const bool rok = (r0 + sr) < N_NODES;
    const float* xrow = &x[(size_t)(r0 + sr) * NFEAT];
    const int swrd = sr * 20 + (tid & 3) * 4;   // LDS write word offset

    // prologue: load + pack + write chunk 0 into buf 0
    {
        uint4 pv = make_uint4(0, 0, 0, 0);
        if (rok) {
            const float4 va = *(const float4*)&xrow[sk];
            const float4 vb = *(const float4*)&xrow[sk + 4];
            pv.x = pack_bf16x2(va.x, va.y);
            pv.y = pack_bf16x2(va.z, va.w);
            pv.z = pack_bf16x2(vb.x, vb.y);
            pv.w = pack_bf16x2(vb.z, vb.w);
        }
        *(uint4*)&xbf[0][swrd] = pv;
    }
    __syncthreads();

#pragma unroll
    for (int kb = 0; kb < 8; kb++) {
        const int cur = kb & 1;
        const int nxt = cur ^ 1;
        // issue next chunk's global loads (in flight during the MFMA phase below;
        // the barrier between issue and use pins this order against the scheduler)
        float4 na = make_float4(0.f, 0.f, 0.f, 0.f);
        float4 nb = make_float4(0.f, 0.f, 0.f, 0.f);
        if (kb < 7 && rok) {
            na = *(const float4*)&xrow[(kb + 1) * 32 + sk];
            nb = *(const float4*)&xrow[(kb + 1) * 32 + sk + 4];
        }
        // MFMA phase: consume buf[cur]
#pragma unroll
        for (int s = 0; s < 4; s++) {
            const uint4 u = *(const uint4*)&xbf[cur][(s * 16 + lm) * 20 + quad * 4];
            const bf16x8 af = *(const bf16x8*)&u;
            acc[s] = __builtin_amdgcn_mfma_f32_16x16x32_bf16(af, bfrag[kb], acc[s], 0, 0, 0);
        }
        // pack + write next chunk into the other buffer (no reader conflict), one barrier
        if (kb < 7) {
            uint4 pv;
            pv.x = pack_bf16x2(na.x, na.y);
            pv.y = pack_bf16x2(na.z, na.w);
            pv.z = pack_bf16x2(nb.x, nb.y);
            pv.w = pack_bf16x2(nb.z, nb.w);
            *(uint4*)&xbf[nxt][swrd] = pv;
            __syncthreads();
        }
    }

    // epilogue: bf16 h1 stores + f32 logit dots (shfl over 8-lane head groups)
    const int head = wv * 2 + (lm >> 3);
    const int jc = l & 7;
    const float asl = a_src[head * NHID + jc];
    const float adl = a_dst[head * NHID + jc];
    const int col = wv * 16 + lm;
#pragma unroll
    for (int s = 0; s < 4; s++) {
#pragma unroll
        for (int r = 0; r < 4; r++) {
            const int row = r0 + s * 16 + quad * 4 + r;
            const float v = acc[s][r];
            float ps = v * asl, pd = v * adl;
            ps += __shfl_xor(ps, 1, 64); pd += __shfl_xor(pd, 1, 64);
            ps += __shfl_xor(ps, 2, 64); pd += __shfl_xor(pd, 2, 64);
            ps += __shfl_xor(ps, 4, 64); pd += __shfl_xor(pd, 4, 64);
            if (row < N_NODES) {
                h1u[(size_t)row * D1 + col] = (ushort)f32_to_bf16_rne(v);
                if (jc == 0) { als[row * HEADS + head] = ps; ald[row * HEADS + head] = pd; }
            }
        }
    }
}

// ---------------- K2: bin edges by dst bucket (LDS hist + chunk reservation) ----------------
// packed entry: (dst&255)<<20 | src   (src < 2^17)
__global__ __launch_bounds__(256) void bin_kernel(const int* __restrict__ ei,
                                                  int* __restrict__ bcur,
                                                  int* __restrict__ bin) {
    __shared__ int lcnt[NBUCK];
    __shared__ int lbase[NBUCK];
    const int tid = threadIdx.x;
    for (int b = tid; b < NBUCK; b += 256) lcnt[b] = 0;
    __syncthreads();
    const int e0 = blockIdx.x * BIN_EPB;
    int pk[BIN_EPT], bk[BIN_EPT], loff[BIN_EPT];
#pragma unroll
    for (int i = 0; i < BIN_EPT; i++) {
        const int e = e0 + i * 256 + tid;
        if (e < E_TOT) {
            int src, dst; edge_src_dst(ei, e, src, dst);
            bk[i] = dst >> BSHIFT;
            pk[i] = ((dst & 255) << 20) | src;
            loff[i] = atomicAdd(&lcnt[bk[i]], 1);
        } else bk[i] = -1;
    }
    __syncthreads();
    for (int b = tid; b < NBUCK; b += 256) {
        const int c = lcnt[b];
        lbase[b] = c ? atomicAdd(&bcur[b], c) : 0;
    }
    __syncthreads();
#pragma unroll
    for (int i = 0; i < BIN_EPT; i++) {
        if (bk[i] >= 0)
            bin[(size_t)bk[i] * BCAP + lbase[bk[i]] + loff[i]] = pk[i];
    }
}

// ---------------- K3: per-bucket LDS counting sort -> dst-sorted CSR ----------------
__global__ __launch_bounds__(256) void bsort_kernel(const int* __restrict__ bcur,
                                                    const int* __restrict__ bin,
                                                    int* __restrict__ csr,
                                                    int* __restrict__ row_ptr,
                                                    int* __restrict__ cnt) {
    __shared__ int hcnt[256];
    __shared__ int hpre[256];
    __shared__ int cur[256];
    __shared__ int ssrc[BCAP];   // 20 KB
    const int tid = threadIdx.x;
    const int bkt = blockIdx.x;
    const int cntb = bcur[bkt];
    const int base = bkt * BCAP;
    hcnt[tid] = 0;
    __syncthreads();
    for (int i = tid; i < cntb; i += 256)
        atomicAdd(&hcnt[bin[base + i] >> 20], 1);
    __syncthreads();
    const int myc = hcnt[tid];
    hpre[tid] = myc;
    __syncthreads();
    for (int off = 1; off < 256; off <<= 1) {
        const int t = (tid >= off) ? hpre[tid - off] : 0;
        __syncthreads();
        hpre[tid] += t;
        __syncthreads();
    }
    const int exc = hpre[tid] - myc;
    cur[tid] = exc;
    __syncthreads();
    for (int i = tid; i < cntb; i += 256) {
        const int v = bin[base + i];
        const int pos = atomicAdd(&cur[v >> 20], 1);
        ssrc[pos] = v & 0xFFFFF;
    }
    __syncthreads();
    for (int i = tid; i < cntb; i += 256) csr[base + i] = ssrc[i];
    const int n = (bkt << BSHIFT) + tid;
    if (n < N_NODES) { row_ptr[n] = base + exc; cnt[n] = myc; }
}

// ---------------- K4: gather layer 1 -- wave/node, 8 lanes x uint4 (head octet), 8 slots ----
// Lane l&7 = head h: one 16B load covers its 8 channels; als[s*8+h] is one distinct float
// per lane (no redundant exp). 2-deep value pipeline: csr 3 ahead, values 2 ahead ->
// 16 h1b loads in flight per wave.
__global__ __launch_bounds__(256) void gather1_kernel(const int* __restrict__ row_ptr,
                                                      const int* __restrict__ cnt,
                                                      const int* __restrict__ csr_src,
                                                      const unsigned* __restrict__ h1b,
                                                      const float* __restrict__ als,
                                                      const float* __restrict__ ald,
                                                      float* __restrict__ out1) {
    const int tid = threadIdx.x;
    const int n = blockIdx.x * 4 + (tid >> 6);   // grid == N_NODES/4 exactly
    const int l = tid & 63;
    const int q = l >> 3;                        // edge slot 0..7
    const int h = l & 7;                         // head = channel octet 8h..8h+7
    const int start = row_ptr[n];
    const int deg = cnt[n];
    const float aldn = ald[n * HEADS + h];
    float a0 = 0.f, a1 = 0.f, a2 = 0.f, a3 = 0.f;
    float a4 = 0.f, a5 = 0.f, a6 = 0.f, a7 = 0.f, wsum = 0.f;

    int i = q;
    float e0 = 0.f, e1 = 0.f;
    uint4 u0 = make_uint4(0u, 0u, 0u, 0u);
    uint4 u1 = make_uint4(0u, 0u, 0u, 0u);
    int s2 = 0;
    if (i < deg) {
        const int s0 = csr_src[start + i];
        e0 = als[s0 * HEADS + h];
        u0 = *(const uint4*)&h1b[(size_t)s0 * 32 + h * 4];
    }
    if (i + 8 < deg) {
        const int s1 = csr_src[start + i + 8];
        e1 = als[s1 * HEADS + h];
        u1 = *(const uint4*)&h1b[(size_t)s1 * 32 + h * 4];
    }
    if (i + 16 < deg) s2 = csr_src[start + i + 16];

    for (; i < deg; i += 8) {
        int s3 = 0;
        if (i + 24 < deg) s3 = csr_src[start + i + 24];
        float e2 = 0.f;
        uint4 u2 = make_uint4(0u, 0u, 0u, 0u);
        if (i + 16 < deg) {
            e2 = als[s2 * HEADS + h];
            u2 = *(const uint4*)&h1b[(size_t)s2 * 32 + h * 4];
        }
        const float w = __expf(lrelu(e0 + aldn));
        const float2 p0 = unpack_bf16x2(u0.x);
        const float2 p1 = unpack_bf16x2(u0.y);
        const float2 p2 = unpack_bf16x2(u0.z);
        const float2 p3 = unpack_bf16x2(u0.w);
        a0 = fmaf(p0.x, w, a0); a1 = fmaf(p0.y, w, a1);
        a2 = fmaf(p1.x, w, a2); a3 = fmaf(p1.y, w, a3);
        a4 = fmaf(p2.x, w, a4); a5 = fmaf(p2.y, w, a5);
        a6 = fmaf(p3.x, w, a6); a7 = fmaf(p3.y, w, a7);
        wsum += w;
        e0 = e1; u0 = u1; e1 = e2; u1 = u2; s2 = s3;
    }

    // reduce across the 8 slots (8-lane groups)
    a0 += __shfl_down(a0, 32, 64); a1 += __shfl_down(a1, 32, 64);
    a2 += __shfl_down(a2, 32, 64); a3 += __shfl_down(a3, 32, 64);
    a4 += __shfl_down(a4, 32, 64); a5 += __shfl_down(a5, 32, 64);
    a6 += __shfl_down(a6, 32, 64); a7 += __shfl_down(a7, 32, 64);
    wsum += __shfl_down(wsum, 32, 64);
    a0 += __shfl_down(a0, 16, 64); a1 += __shfl_down(a1, 16, 64);
    a2 += __shfl_down(a2, 16, 64); a3 += __shfl_down(a3, 16, 64);
    a4 += __shfl_down(a4, 16, 64); a5 += __shfl_down(a5, 16, 64);
    a6 += __shfl_down(a6, 16, 64); a7 += __shfl_down(a7, 16, 64);
    wsum += __shfl_down(wsum, 16, 64);
    a0 += __shfl_down(a0, 8, 64); a1 += __shfl_down(a1, 8, 64);
    a2 += __shfl_down(a2, 8, 64); a3 += __shfl_down(a3, 8, 64);
    a4 += __shfl_down(a4, 8, 64); a5 += __shfl_down(a5, 8, 64);
    a6 += __shfl_down(a6, 8, 64); a7 += __shfl_down(a7, 8, 64);
    wsum += __shfl_down(wsum, 8, 64);
    if (l < 8) {
        const float inv = 1.f / (wsum + 1e-16f);
        float* op = &out1[(size_t)n * D1 + h * 8];
        *(float4*)&op[0] = make_float4(a0 * inv, a1 * inv, a2 * inv, a3 * inv);
        *(float4*)&op[4] = make_float4(a4 * inv, a5 * inv, a6 * inv, a7 * inv);
    }
}

// ---------------- K5: z = elu(out1+b1); h2 = z @ W2 (bf16-packed); layer-2 logits ----------
__global__ __launch_bounds__(256) void layer2_node_kernel(const float* __restrict__ out1,
                                                          const float* __restrict__ b1,
                                                          const float* __restrict__ W2,
                                                          const float* __restrict__ a_src2,
                                                          const float* __restrict__ a_dst2,
                                                          unsigned* __restrict__ h2b,
                                                          float* __restrict__ als2,
                                                          float* __restrict__ ald2) {
    __shared__ float w2l[D1 * NCLASS];   // 8 KB
    __shared__ float b1l[D1];
    __shared__ float a2l[2 * NCLASS];
    const int tid = threadIdx.x;
    for (int i = tid; i < D1 * NCLASS; i += 256) w2l[i] = W2[i];
    if (tid < D1) b1l[tid] = b1[tid];
    if (tid < NCLASS) a2l[tid] = a_src2[tid];
    else if (tid < 2 * NCLASS) a2l[tid] = a_dst2[tid - NCLASS];
    __syncthreads();

    const int n = blockIdx.x * 256 + tid;
    if (n >= N_NODES) return;
    float acc[NCLASS];
#pragma unroll
    for (int c = 0; c < NCLASS; c++) acc[c] = 0.f;
    float as = 0.f, ad = 0.f;
    const float4* rp = (const float4*)&out1[(size_t)n * D1];
#pragma unroll 2
    for (int k4 = 0; k4 < 16; k4++) {
        const float4 v4 = rp[k4];
        const float vv[4] = {v4.x, v4.y, v4.z, v4.w};
#pragma unroll
        for (int j = 0; j < 4; j++) {
            const int k = k4 * 4 + j;
            float z = vv[j] + b1l[k];
            z = z > 0.f ? z : expm1f(z);   // jax.nn.elu
            const float* wr = &w2l[k * NCLASS];
#pragma unroll
            for (int c = 0; c < NCLASS; c++) acc[c] += z * wr[c];
        }
    }
#pragma unroll
    for (int c = 0; c < NCLASS; c++) { as += acc[c] * a2l[c]; ad += acc[c] * a2l[NCLASS + c]; }
#pragma unroll
    for (int q = 0; q < 4; q++) {
        uint4 pv;
        pv.x = pack_bf16x2(acc[q * 8 + 0], acc[q * 8 + 1]);
        pv.y = pack_bf16x2(acc[q * 8 + 2], acc[q * 8 + 3]);
        pv.z = pack_bf16x2(acc[q * 8 + 4], acc[q * 8 + 5]);
        pv.w = pack_bf16x2(acc[q * 8 + 6], acc[q * 8 + 7]);
        *(uint4*)&h2b[(size_t)n * 16 + q * 4] = pv;
    }
    als2[n] = as; ald2[n] = ad;
}

// ---------------- K6: gather layer 2 -- wave/node, 4 lanes x uint4 (8ch), 16 edge slots ----
__global__ __launch_bounds__(256) void gather2_kernel(const int* __restrict__ row_ptr,
                                                      const int* __restrict__ cnt,
                                                      const int* __restrict__ csr_src,
                                                      const unsigned* __restrict__ h2b,
                                                      const float* __restrict__ als2,
                                                      const float* __restrict__ ald2,
                                                      float* __restrict__ out2) {
    const int tid = threadIdx.x;
    const int n = blockIdx.x * 4 + (tid >> 6);   // grid == N_NODES/4 exactly
    const int l = tid & 63;
    const int q = l >> 2;                        // edge slot 0..15
    const int c = l & 3;                         // channel octet: ch 8c..8c+7
    const int start = row_ptr[n];
    const int deg = cnt[n];
    const float aldn = ald2[n];
    float a0 = 0.f, a1 = 0.f, a2 = 0.f, a3 = 0.f;
    float a4 = 0.f, a5 = 0.f, a6 = 0.f, a7 = 0.f, wsum = 0.f;

    int i = q;
    float e0 = 0.f, e1 = 0.f;
    uint4 u0 = make_uint4(0u, 0u, 0u, 0u);
    uint4 u1 = make_uint4(0u, 0u, 0u, 0u);
    int s2 = 0;
    if (i < deg) {
        const int s0 = csr_src[start + i];
        e0 = als2[s0];
        u0 = *(const uint4*)&h2b[(size_t)s0 * 16 + c * 4];
    }
    if (i + 16 < deg) {
        const int s1 = csr_src[start + i + 16];
        e1 = als2[s1];
        u1 = *(const uint4*)&h2b[(size_t)s1 * 16 + c * 4];
    }
    if (i + 32 < deg) s2 = csr_src[start + i + 32];

    for (; i < deg; i += 16) {
        int s3 = 0;
        if (i + 48 < deg) s3 = csr_src[start + i + 48];
        float e2 = 0.f;
        uint4 u2 = make_uint4(0u, 0u, 0u, 0u);
        if (i + 32 < deg) {
            e2 = als2[s2];
            u2 = *(const uint4*)&h2b[(size_t)s2 * 16 + c * 4];
        }
        const float w = __expf(lrelu(e0 + aldn));
        const float2 p0 = unpack_bf16x2(u0.x);
        const float2 p1 = unpack_bf16x2(u0.y);
        const float2 p2 = unpack_bf16x2(u0.z);
        const float2 p3 = unpack_bf16x2(u0.w);
        a0 = fmaf(p0.x, w, a0); a1 = fmaf(p0.y, w, a1);
        a2 = fmaf(p1.x, w, a2); a3 = fmaf(p1.y, w, a3);
        a4 = fmaf(p2.x, w, a4); a5 = fmaf(p2.y, w, a5);
        a6 = fmaf(p3.x, w, a6); a7 = fmaf(p3.y, w, a7);
        wsum += w;
        e0 = e1; u0 = u1; e1 = e2; u1 = u2; s2 = s3;
    }

    // reduce across the 16 slots (4-lane groups)
    a0 += __shfl_down(a0, 32, 64); a1 += __shfl_down(a1, 32, 64);
    a2 += __shfl_down(a2, 32, 64); a3 += __shfl_down(a3, 32, 64);
    a4 += __shfl_down(a4, 32, 64); a5 += __shfl_down(a5, 32, 64);
    a6 += __shfl_down(a6, 32, 64); a7 += __shfl_down(a7, 32, 64);
    wsum += __shfl_down(wsum, 32, 64);
    a0 += __shfl_down(a0, 16, 64); a1 += __shfl_down(a1, 16, 64);
    a2 += __shfl_down(a2, 16, 64); a3 += __shfl_down(a3, 16, 64);
    a4 += __shfl_down(a4, 16, 64); a5 += __shfl_down(a5, 16, 64);
    a6 += __shfl_down(a6, 16, 64); a7 += __shfl_down(a7, 16, 64);
    wsum += __shfl_down(wsum, 16, 64);
    a0 += __shfl_down(a0, 8, 64); a1 += __shfl_down(a1, 8, 64);
    a2 += __shfl_down(a2, 8, 64); a3 += __shfl_down(a3, 8, 64);
    a4 += __shfl_down(a4, 8, 64); a5 += __shfl_down(a5, 8, 64);
    a6 += __shfl_down(a6, 8, 64); a7 += __shfl_down(a7, 8, 64);
    wsum += __shfl_down(wsum, 8, 64);
    a0 += __shfl_down(a0, 4, 64); a1 += __shfl_down(a1, 4, 64);
    a2 += __shfl_down(a2, 4, 64); a3 += __shfl_down(a3, 4, 64);
    a4 += __shfl_down(a4, 4, 64); a5 += __shfl_down(a5, 4, 64);
    a6 += __shfl_down(a6, 4, 64); a7 += __shfl_down(a7, 4, 64);
    wsum += __shfl_down(wsum, 4, 64);
    if (l < 4) {
        const float inv = 1.f / (wsum + 1e-16f);
        float* op = &out2[(size_t)n * NCLASS + c * 8];
        *(float4*)&op[0] = make_float4(a0 * inv, a1 * inv, a2 * inv, a3 * inv);
        *(float4*)&op[4] = make_float4(a4 * inv, a5 * inv, a6 * inv, a7 * inv);
    }
}

// ---------------- K7: + b2, log_softmax ----------------
__global__ __launch_bounds__(256) void logsoftmax_kernel(const float* __restrict__ out2,
                                                         const float* __restrict__ b2,
                                                         float* __restrict__ out) {
    __shared__ float b2l[NCLASS];
    if (threadIdx.x < NCLASS) b2l[threadIdx.x] = b2[threadIdx.x];
    __syncthreads();
    const int n = blockIdx.x * 256 + threadIdx.x;
    if (n >= N_NODES) return;
    float v[NCLASS];
    float mx = -INFINITY;
    const float4* rp = (const float4*)&out2[(size_t)n * NCLASS];
#pragma unroll
    for (int c4 = 0; c4 < NCLASS / 4; c4++) {
        const float4 t = rp[c4];
        v[c4 * 4 + 0] = t.x + b2l[c4 * 4 + 0];
        v[c4 * 4 + 1] = t.y + b2l[c4 * 4 + 1];
        v[c4 * 4 + 2] = t.z + b2l[c4 * 4 + 2];
        v[c4 * 4 + 3] = t.w + b2l[c4 * 4 + 3];
    }
#pragma unroll
    for (int c = 0; c < NCLASS; c++) mx = fmaxf(mx, v[c]);
    float s = 0.f;
#pragma unroll
    for (int c = 0; c < NCLASS; c++) s += __expf(v[c] - mx);
    const float lse = mx + logf(s);
    float4* op = (float4*)&out[(size_t)n * NCLASS];
#pragma unroll
    for (int c4 = 0; c4 < NCLASS / 4; c4++)
        op[c4] = make_float4(v[c4 * 4] - lse, v[c4 * 4 + 1] - lse, v[c4 * 4 + 2] - lse, v[c4 * 4 + 3] - lse);
}

extern "C" void kernel_launch(void* const* d_in, const int* in_sizes, int n_in,
                              void* d_out, int out_size, void* d_ws, size_t ws_size,
                              hipStream_t stream) {
    const float* x      = (const float*)d_in[0];
    const int*   ei     = (const int*)d_in[1];
    const float* W1     = (const float*)d_in[2];
    const float* a_src1 = (const float*)d_in[3];
    const float* a_dst1 = (const float*)d_in[4];
    const float* b1     = (const float*)d_in[5];
    const float* W2     = (const float*)d_in[6];
    const float* a_src2 = (const float*)d_in[7];
    const float* a_dst2 = (const float*)d_in[8];
    const float* b2     = (const float*)d_in[9];
    float* out = (float*)d_out;
    float* ws  = (float*)d_ws;

    ushort* h1u     = (ushort*)(ws + OFF_H1);
    unsigned* h1b   = (unsigned*)(ws + OFF_H1);
    float* out1     = ws + OFF_OUT1;
    float* als1     = ws + OFF_ALS1;
    float* ald1     = ws + OFF_ALD1;
    float* als2     = ws + OFF_ALS2;
    float* ald2     = ws + OFF_ALD2;
    int*   bcur     = (int*)(ws + OFF_BCUR);
    int*   row_ptr  = (int*)(ws + OFF_ROWP);
    int*   cnt      = (int*)(ws + OFF_CNT);
    int*   bin      = (int*)(ws + OFF_BIN);
    int*   csr      = (int*)(ws + OFF_CSR);
    unsigned* h2b   = (unsigned*)(ws + OFF_H1);          // alias: h1b dead after gather1
    float* out2     = ws + OFF_H1 + 3200000;             // beyond h2b's 1.6M uints

    hipMemsetAsync(bcur, 0, NBUCK * sizeof(int), stream);

    const int NB = (N_NODES + 255) / 256;   // 391

    gemm1_kernel<<<(N_NODES + 63) / 64, 256, 0, stream>>>(x, W1, a_src1, a_dst1, h1u, als1, ald1);
    bin_kernel<<<(E_TOT + BIN_EPB - 1) / BIN_EPB, 256, 0, stream>>>(ei, bcur, bin);
    bsort_kernel<<<NBUCK, 256, 0, stream>>>(bcur, bin, csr, row_ptr, cnt);
    gather1_kernel<<<N_NODES / 4, 256, 0, stream>>>(row_ptr, cnt, csr, h1b, als1, ald1, out1);
    layer2_node_kernel<<<NB, 256, 0, stream>>>(out1, b1, W2, a_src2, a_dst2, h2b, als2, ald2);
    gather2_kernel<<<N_NODES / 4, 256, 0, stream>>>(row_ptr, cnt, csr, h2b, als2, ald2, out2);
    logsoftmax_kernel<<<NB, 256, 0, stream>>>(out2, b2, out);
}